// Round 17
// baseline (189.997 us; speedup 1.0000x reference)
//
#include <hip/hip_runtime.h>

#define BB 2
#define CH_FEAT 128
#define HEADS 4
#define DH 64
#define INNER 256
#define NPOS 13824   // 24^3
#define MPOS 512     // 8^3
#define DSZ 24
#define JSPLIT 27    // col-pass j chunks (432 col blocks, uniform with row blocks)
#define JCHUNK (NPOS / JSPLIT)  // 512
#define QSCALE (0.125f * 1.44269504088896340736f)  // fold 1/ln2: exp(s)=exp2(s')

typedef __attribute__((ext_vector_type(8))) short bf16x8;
typedef __attribute__((ext_vector_type(4))) float f32x4;

__device__ inline unsigned short bf16_rn(float x) {
  unsigned u = __builtin_bit_cast(unsigned, x);
  u += 0x7FFF + ((u >> 16) & 1);
  return (unsigned short)(u >> 16);
}
__device__ inline unsigned pk_bf16(float a, float b) {
  return (unsigned)bf16_rn(a) | ((unsigned)bf16_rn(b) << 16);
}
__device__ inline float bf2f(unsigned short u) {
  return __builtin_bit_cast(float, (unsigned)u << 16);
}

// async global->LDS 16B (dest must be wave-uniform base + lane*16)
#define GL2LDS(g, l)                                                        \
  __builtin_amdgcn_global_load_lds(                                         \
      (const __attribute__((address_space(1))) void*)(g),                   \
      (__attribute__((address_space(3))) void*)(l), 16, 0, 0)

// swizzled read of a 16B fragment from a [rows][pitch B] LDS tile
__device__ inline bf16x8 lds_frag(const char* tile, int row, int colb) {
  return *(const bf16x8*)(tile + row * 128 + (colb ^ ((row & 7) << 4)));
}
__device__ inline bf16x8 lds_fragP(const char* tile, int row, int colb, int pitch) {
  return *(const bf16x8*)(tile + row * pitch + (colb ^ ((row & 7) << 4)));
}

// ================= FUSED PRE: map_qv (blocks [0,1024)) + dwf (rest) ========
__global__ __launch_bounds__(256) void k_pre(const float* __restrict__ smap,
                                             const float* __restrict__ mqv_w,
                                             unsigned short* __restrict__ mapqb,
                                             unsigned short* __restrict__ mapvTb,
                                             const float* __restrict__ feat,
                                             const float* __restrict__ fqv_dw,
                                             unsigned short* __restrict__ dwt) {
  int bid = blockIdx.x;
  int t = threadIdx.x;
  if (bid < 1024) {
    int b = bid >> 9, m = bid & 511;
    __shared__ float s[64];
    if (t < 64) s[t] = smap[(size_t)(b * 64 + t) * MPOS + m];
    __syncthreads();
#pragma unroll
    for (int half = 0; half < 2; ++half) {
      int co2 = half * 256 + t;
      const float* wr = mqv_w + (size_t)co2 * 64;
      float acc = 0.f;
#pragma unroll
      for (int c = 0; c < 64; ++c) acc += wr[c] * s[c];
      int qv = co2 >> 8, c2 = co2 & 255, head = c2 & 3, dh = c2 >> 2;
      int bh = b * HEADS + head;
      if (qv == 0)
        mapqb[((size_t)bh * MPOS + m) * 64 + dh] = bf16_rn(acc * QSCALE);
      else
        mapvTb[((size_t)bh * 64 + dh) * MPOS + m] = bf16_rn(acc);
    }
  } else {
    int tid = (bid - 1024) * 256 + t;
    int bc = tid / 1728;
    int s = tid - bc * 1728;
    int c = bc & (CH_FEAT - 1);
    int xs = (s % 3) * 8;
    int row = s / 3;
    int y = row % 24, z = row / 24;
    const float* wr = fqv_dw + c * 27;
    const float* ip = feat + (size_t)bc * NPOS;

    float w0a[9], w1a[9], w2a[9];
    int ro[9];
#pragma unroll
    for (int dz = 0; dz < 3; ++dz)
#pragma unroll
      for (int dy = 0; dy < 3; ++dy) {
        int r = dz * 3 + dy;
        int zz = z + dz - 1, yy = y + dy - 1;
        bool ok = ((unsigned)zz < 24u) && ((unsigned)yy < 24u);
        w0a[r] = ok ? wr[dz * 9 + dy * 3 + 0] : 0.f;
        w1a[r] = ok ? wr[dz * 9 + dy * 3 + 1] : 0.f;
        w2a[r] = ok ? wr[dz * 9 + dy * 3 + 2] : 0.f;
        int zc = min(max(zz, 0), 23), yc = min(max(yy, 0), 23);
        ro[r] = (zc * 24 + yc) * 24;
      }
    float4 Bv[9], Cv[9];
    float xm1[9], x8[9];
#pragma unroll
    for (int r = 0; r < 9; ++r) {
      Bv[r] = *(const float4*)(ip + ro[r] + xs);
      Cv[r] = *(const float4*)(ip + ro[r] + xs + 4);
      xm1[r] = xs ? *(ip + ro[r] + xs - 1) : 0.f;
      x8[r] = (xs < 16) ? *(ip + ro[r] + xs + 8) : 0.f;
    }
    float acc[8];
#pragma unroll
    for (int i = 0; i < 8; ++i) acc[i] = 0.f;
#pragma unroll
    for (int r = 0; r < 9; ++r) {
      float xv[10] = {xm1[r], Bv[r].x, Bv[r].y, Bv[r].z, Bv[r].w,
                      Cv[r].x, Cv[r].y, Cv[r].z, Cv[r].w, x8[r]};
#pragma unroll
      for (int i = 0; i < 8; ++i)
        acc[i] += w0a[r] * xv[i] + w1a[r] * xv[i + 1] + w2a[r] * xv[i + 2];
    }
    unsigned short* op = dwt + (size_t)bc * NPOS + row * 24 + xs;
    uint4 pv;
    pv.x = pk_bf16(acc[0], acc[1]);
    pv.y = pk_bf16(acc[2], acc[3]);
    pv.z = pk_bf16(acc[4], acc[5]);
    pv.w = pk_bf16(acc[6], acc[7]);
    *(uint4*)op = pv;
  }
}

// ---------------- MFMA pointwise qv GEMM (fused in-LDS transpose) ---------
__global__ __launch_bounds__(256) void k_pwqv_m(const unsigned short* __restrict__ dwt,
                                                const float* __restrict__ pw,
                                                unsigned short* __restrict__ fqb,
                                                unsigned short* __restrict__ fvTb) {
  __shared__ __align__(16) char sW[16384];
  __shared__ __align__(16) char sR[32768];
  __shared__ __align__(16) char sB[32768];
  int t = threadIdx.x, wave = t >> 6, lane = t & 63, g = lane >> 4, c = lane & 15;
  int n0 = blockIdx.x * 128, ti = blockIdx.y, b = blockIdx.z;
  int qv = ti >> 2, head = ti & 3, bh = b * 4 + head;

  {
    int r = t >> 2, ks = (t & 3) * 32;
    int co = qv * 256 + r * 4 + head;
    const float* wp = pw + (size_t)co * 128 + ks;
    unsigned pkv[16];
#pragma unroll
    for (int i = 0; i < 8; ++i) {
      float4 v = *(const float4*)(wp + i * 4);
      pkv[2 * i] = pk_bf16(v.x, v.y);
      pkv[2 * i + 1] = pk_bf16(v.z, v.w);
    }
#pragma unroll
    for (int u = 0; u < 4; ++u) {
      int colb = (ks * 2 + u * 16) ^ ((r & 7) << 4);
      *(uint4*)(sW + r * 256 + colb) = *(uint4*)&pkv[u * 4];
    }
  }
  const char* Bgc = (const char*)(dwt + (size_t)b * CH_FEAT * NPOS);
#pragma unroll
  for (int p = 0; p < 8; ++p) {
    int oo = p * 4096 + t * 16;
    int k = oo >> 8, col = oo & 255;
    GL2LDS(Bgc + (size_t)k * (NPOS * 2) + n0 * 2 + col, sR + oo);
  }
  __syncthreads();

  {
    const unsigned short* R16 = (const unsigned short*)sR;
#pragma unroll
    for (int it = 0; it < 8; ++it) {
      int cid = it * 256 + t;
      int n = cid & 127, kc16 = (cid >> 7) & 15;
      unsigned short v[8];
#pragma unroll
      for (int j = 0; j < 8; ++j) v[j] = R16[(kc16 * 8 + j) * 128 + n];
      unsigned u4[4];
#pragma unroll
      for (int i = 0; i < 4; ++i)
        u4[i] = (unsigned)v[2 * i] | ((unsigned)v[2 * i + 1] << 16);
      *(uint4*)(sB + n * 256 + ((kc16 * 16) ^ ((n & 7) << 4))) = *(uint4*)&u4[0];
    }
  }
  __syncthreads();

  f32x4 acc[4][2];
#pragma unroll
  for (int ct = 0; ct < 4; ++ct)
#pragma unroll
    for (int jf = 0; jf < 2; ++jf) acc[ct][jf] = (f32x4){0.f, 0.f, 0.f, 0.f};
  int nw = wave * 32;
#pragma unroll
  for (int kc = 0; kc < 4; ++kc) {
    bf16x8 bq[2];
#pragma unroll
    for (int jf = 0; jf < 2; ++jf)
      bq[jf] = lds_fragP(sB, nw + jf * 16 + c, kc * 64 + g * 16, 256);
#pragma unroll
    for (int ct = 0; ct < 4; ++ct) {
      bf16x8 a = lds_fragP(sW, ct * 16 + c, kc * 64 + g * 16, 256);
#pragma unroll
      for (int jf = 0; jf < 2; ++jf)
        acc[ct][jf] = __builtin_amdgcn_mfma_f32_16x16x32_bf16(a, bq[jf], acc[ct][jf], 0, 0, 0);
    }
  }
  __syncthreads();

  char* dmp = sR;
#pragma unroll
  for (int ct = 0; ct < 4; ++ct)
#pragma unroll
    for (int jf = 0; jf < 2; ++jf) {
      int n = nw + jf * 16 + c;
      uint2 wv;
      wv.x = pk_bf16(acc[ct][jf][0], acc[ct][jf][1]);
      wv.y = pk_bf16(acc[ct][jf][2], acc[ct][jf][3]);
      *(uint2*)(dmp + n * 144 + (ct * 16 + 4 * g) * 2) = wv;
    }
  __syncthreads();

  if (qv == 0) {
    int nr = t >> 1, seg = t & 1;
    const char* src = dmp + nr * 144 + seg * 64;
    unsigned short* dst = fqb + ((size_t)bh * NPOS + n0 + nr) * 64 + seg * 32;
#pragma unroll
    for (int i = 0; i < 4; ++i)
      *(uint4*)(dst + i * 8) = *(const uint4*)(src + i * 16);
  } else {
#pragma unroll
    for (int it = 0; it < 2; ++it) {
      int idx = it * 256 + t;
      int dh = idx >> 3, nseg = (idx & 7) * 16;
      unsigned pkv[8];
#pragma unroll
      for (int i = 0; i < 8; ++i) {
        unsigned short lo = *(const unsigned short*)(dmp + (nseg + 2 * i) * 144 + dh * 2);
        unsigned short hi = *(const unsigned short*)(dmp + (nseg + 2 * i + 1) * 144 + dh * 2);
        pkv[i] = (unsigned)lo | ((unsigned)hi << 16);
      }
      unsigned short* dst = fvTb + ((size_t)bh * 64 + dh) * NPOS + n0 + nseg;
      *(uint4*)(dst) = *(uint4*)&pkv[0];
      *(uint4*)(dst + 8) = *(uint4*)&pkv[4];
    }
  }
}

// ================= FUSED ATTENTION (512 threads, 8 waves, 3 blocks/CU) =====
// row pass: blocks [0,432); col pass: blocks [432,864)
// sP halved via ks-subphase restructure (wave-private, no extra barriers)
__global__ __launch_bounds__(512, 4) void k_attn(const unsigned short* __restrict__ fqb,
                                                 const unsigned short* __restrict__ fvTb,
                                                 const unsigned short* __restrict__ mapqb,
                                                 const unsigned short* __restrict__ mapvTb,
                                                 unsigned short* __restrict__ F,
                                                 float* __restrict__ Gc,
                                                 float* __restrict__ Gl) {
  __shared__ __align__(16) char sAll[52224];  // [0,32K) dbuf | sP 18KB | sL 1KB
  char* sPool = sAll;
  unsigned (*sP)[2][16][18] = (unsigned (*)[2][16][18])(sAll + 32768);
  float (*sL)[2][16] = (float (*)[2][16])(sAll + 32768 + 18432);
  int bid = blockIdx.x;
  int t = threadIdx.x, wave = t >> 6, lane = t & 63, g = lane >> 4, c = lane & 15;

  if (bid < 432) {  // ========== ROW PASS ==========
    int jblk = bid % 54, bh = bid / 54;
    int j0 = jblk * 256 + wave * 32;

    const char* Kg = (const char*)(mapqb + (size_t)bh * MPOS * 64);
    const char* Vg = (const char*)(mapvTb + (size_t)bh * 64 * MPOS);

    const unsigned short* fqp = fqb + ((size_t)bh * NPOS + j0 + c) * 64 + 8 * g;
    bf16x8 bq00 = *(const bf16x8*)(fqp);
    bf16x8 bq01 = *(const bf16x8*)(fqp + 32);
    bf16x8 bq10 = *(const bf16x8*)(fqp + 16 * 64);
    bf16x8 bq11 = *(const bf16x8*)(fqp + 16 * 64 + 32);

    f32x4 o[2][4];
#pragma unroll
    for (int jf = 0; jf < 2; ++jf)
#pragma unroll
      for (int dt = 0; dt < 4; ++dt) o[jf][dt] = (f32x4){0.f, 0.f, 0.f, 0.f};
    float ls0 = 0.f, ls1 = 0.f;

    {
      int oo = t * 16;
      int row = oo >> 7, col = (oo & 127) ^ (((oo >> 7) & 7) << 4);
      GL2LDS(Kg + (size_t)row * 128 + col, sPool + oo);
      GL2LDS(Vg + (size_t)row * 1024 + col, sPool + 16384 + oo);
    }
    __syncthreads();

    for (int ic = 0; ic < 8; ++ic) {
      const char* Kt = sPool + (ic & 1) * 8192;
      const char* Vt = sPool + 16384 + (ic & 1) * 8192;
      if (ic < 7) {
        int ibase = (ic + 1) * 64;
        int bsel = ((ic + 1) & 1) * 8192;
        int oo = t * 16;
        int row = oo >> 7, col = (oo & 127) ^ (((oo >> 7) & 7) << 4);
        GL2LDS(Kg + (size_t)(ibase + row) * 128 + col, sPool + bsel + oo);
        GL2LDS(Vg + (size_t)row * 1024 + ibase * 2 + col, sPool + 16384 + bsel + oo);
      }
#pragma unroll
      for (int ks = 0; ks < 2; ++ks) {
#pragma unroll
        for (int tt = 0; tt < 2; ++tt) {
          int ti = ks * 2 + tt;
          bf16x8 a0 = lds_frag(Kt, ti * 16 + c, 16 * g);
          bf16x8 a1 = lds_frag(Kt, ti * 16 + c, 64 + 16 * g);
          f32x4 s0 = {0.f, 0.f, 0.f, 0.f}, s1 = {0.f, 0.f, 0.f, 0.f};
          __builtin_amdgcn_s_setprio(1);
          s0 = __builtin_amdgcn_mfma_f32_16x16x32_bf16(a0, bq00, s0, 0, 0, 0);
          s0 = __builtin_amdgcn_mfma_f32_16x16x32_bf16(a1, bq01, s0, 0, 0, 0);
          s1 = __builtin_amdgcn_mfma_f32_16x16x32_bf16(a0, bq10, s1, 0, 0, 0);
          s1 = __builtin_amdgcn_mfma_f32_16x16x32_bf16(a1, bq11, s1, 0, 0, 0);
          __builtin_amdgcn_s_setprio(0);
          float p0 = __builtin_amdgcn_exp2f(s0[0]), p1 = __builtin_amdgcn_exp2f(s0[1]);
          float p2 = __builtin_amdgcn_exp2f(s0[2]), p3 = __builtin_amdgcn_exp2f(s0[3]);
          ls0 += (p0 + p1) + (p2 + p3);
          sP[wave][0][c][tt * 8 + 2 * g] = pk_bf16(p0, p1);
          sP[wave][0][c][tt * 8 + 2 * g + 1] = pk_bf16(p2, p3);
          float q0 = __builtin_amdgcn_exp2f(s1[0]), q1 = __builtin_amdgcn_exp2f(s1[1]);
          float q2 = __builtin_amdgcn_exp2f(s1[2]), q3 = __builtin_amdgcn_exp2f(s1[3]);
          ls1 += (q0 + q1) + (q2 + q3);
          sP[wave][1][c][tt * 8 + 2 * g] = pk_bf16(q0, q1);
          sP[wave][1][c][tt * 8 + 2 * g + 1] = pk_bf16(q2, q3);
        }
        bf16x8 ap0 = *(const bf16x8*)&sP[wave][0][c][4 * g];
        bf16x8 ap1 = *(const bf16x8*)&sP[wave][1][c][4 * g];
        __builtin_amdgcn_s_setprio(1);
#pragma unroll
        for (int dt = 0; dt < 4; ++dt) {
          bf16x8 bv = lds_frag(Vt, dt * 16 + c, ks * 64 + 16 * g);
          o[0][dt] = __builtin_amdgcn_mfma_f32_16x16x32_bf16(ap0, bv, o[0][dt], 0, 0, 0);
          o[1][dt] = __builtin_amdgcn_mfma_f32_16x16x32_bf16(ap1, bv, o[1][dt], 0, 0, 0);
        }
        __builtin_amdgcn_s_setprio(0);
      }
      __syncthreads();
    }

    ls0 += __shfl_xor(ls0, 16); ls0 += __shfl_xor(ls0, 32);
    ls1 += __shfl_xor(ls1, 16); ls1 += __shfl_xor(ls1, 32);
    if (g == 0) { sL[wave][0][c] = 1.f / ls0; sL[wave][1][c] = 1.f / ls1; }
#pragma unroll
    for (int jf = 0; jf < 2; ++jf) {
      float rl0 = sL[wave][jf][4 * g + 0], rl1 = sL[wave][jf][4 * g + 1];
      float rl2 = sL[wave][jf][4 * g + 2], rl3 = sL[wave][jf][4 * g + 3];
#pragma unroll
      for (int dt = 0; dt < 4; ++dt) {
        uint2 wv;
        wv.x = pk_bf16(o[jf][dt][0] * rl0, o[jf][dt][1] * rl1);
        wv.y = pk_bf16(o[jf][dt][2] * rl2, o[jf][dt][3] * rl3);
        *(uint2*)(sAll + (dt * 16 + c) * 544 + (wave * 32 + jf * 16 + 4 * g) * 2) = wv;
      }
    }
    __syncthreads();
    {
      int ch = t >> 3, seg = t & 7;
      int b = bh >> 2, head = bh & 3;
      unsigned short* dst = F + ((size_t)b * INNER + head * 64 + ch) * NPOS +
                            jblk * 256 + seg * 32;
      const char* src = sAll + ch * 544 + seg * 64;
#pragma unroll
      for (int i = 0; i < 4; ++i)
        *(uint4*)(dst + i * 8) = *(const uint4*)(src + i * 16);
    }
  } else {  // ========== COL PASS (bh-fastest for XCD pinning) ==========
    int cid = bid - 432;
    int bh = cid & 7, iblk = (cid >> 3) & 1, chunk = cid >> 4;
    char* sQ = sPool;
    char* sV = sPool + 16384;
    int i0 = iblk * 256 + wave * 32;
    int jb = chunk * JCHUNK;

    const char* Qg = (const char*)(fqb + (size_t)bh * NPOS * 64);
    const char* Vg = (const char*)(fvTb + (size_t)bh * 64 * NPOS);

    const unsigned short* kp = mapqb + ((size_t)bh * MPOS + i0 + c) * 64 + 8 * g;
    bf16x8 bm00 = *(const bf16x8*)(kp);
    bf16x8 bm01 = *(const bf16x8*)(kp + 32);
    bf16x8 bm10 = *(const bf16x8*)(kp + 16 * 64);
    bf16x8 bm11 = *(const bf16x8*)(kp + 16 * 64 + 32);

    f32x4 o[2][4];
#pragma unroll
    for (int f = 0; f < 2; ++f)
#pragma unroll
      for (int dt = 0; dt < 4; ++dt) o[f][dt] = (f32x4){0.f, 0.f, 0.f, 0.f};
    float lc0 = 0.f, lc1 = 0.f;

    {
      int oo = t * 16;
      int row = oo >> 7, col = (oo & 127) ^ (((oo >> 7) & 7) << 4);
      GL2LDS(Qg + (size_t)(jb + row) * 128 + col, sQ + oo);
      GL2LDS(Vg + (size_t)row * (NPOS * 2) + jb * 2 + col, sV + oo);
    }
    __syncthreads();

    for (int jc = 0; jc < JCHUNK / 64; ++jc) {
      const char* Qt = sQ + (jc & 1) * 8192;
      const char* Vt = sV + (jc & 1) * 8192;
      if (jc < JCHUNK / 64 - 1) {
        int jbase = jb + (jc + 1) * 64;
        int bsel = ((jc + 1) & 1) * 8192;
        int oo = t * 16;
        int row = oo >> 7, col = (oo & 127) ^ (((oo >> 7) & 7) << 4);
        GL2LDS(Qg + (size_t)(jbase + row) * 128 + col, sQ + bsel + oo);
        GL2LDS(Vg + (size_t)row * (NPOS * 2) + jbase * 2 + col, sV + bsel + oo);
      }
#pragma unroll
      for (int ks = 0; ks < 2; ++ks) {
#pragma unroll
        for (int tt = 0; tt < 2; ++tt) {
          int tj = ks * 2 + tt;
          bf16x8 a0 = lds_frag(Qt, tj * 16 + c, 16 * g);
          bf16x8 a1 = lds_frag(Qt, tj * 16 + c, 64 + 16 * g);
          f32x4 s0 = {0.f, 0.f, 0.f, 0.f}, s1 = {0.f, 0.f, 0.f, 0.f};
          __builtin_amdgcn_s_setprio(1);
          s0 = __builtin_amdgcn_mfma_f32_16x16x32_bf16(a0, bm00, s0, 0, 0, 0);
          s0 = __builtin_amdgcn_mfma_f32_16x16x32_bf16(a1, bm01, s0, 0, 0, 0);
          s1 = __builtin_amdgcn_mfma_f32_16x16x32_bf16(a0, bm10, s1, 0, 0, 0);
          s1 = __builtin_amdgcn_mfma_f32_16x16x32_bf16(a1, bm11, s1, 0, 0, 0);
          __builtin_amdgcn_s_setprio(0);
          float p0 = __builtin_amdgcn_exp2f(s0[0]), p1 = __builtin_amdgcn_exp2f(s0[1]);
          float p2 = __builtin_amdgcn_exp2f(s0[2]), p3 = __builtin_amdgcn_exp2f(s0[3]);
          lc0 += (p0 + p1) + (p2 + p3);
          sP[wave][0][c][tt * 8 + 2 * g] = pk_bf16(p0, p1);
          sP[wave][0][c][tt * 8 + 2 * g + 1] = pk_bf16(p2, p3);
          float q0 = __builtin_amdgcn_exp2f(s1[0]), q1 = __builtin_amdgcn_exp2f(s1[1]);
          float q2 = __builtin_amdgcn_exp2f(s1[2]), q3 = __builtin_amdgcn_exp2f(s1[3]);
          lc1 += (q0 + q1) + (q2 + q3);
          sP[wave][1][c][tt * 8 + 2 * g] = pk_bf16(q0, q1);
          sP[wave][1][c][tt * 8 + 2 * g + 1] = pk_bf16(q2, q3);
        }
        bf16x8 ap0 = *(const bf16x8*)&sP[wave][0][c][4 * g];
        bf16x8 ap1 = *(const bf16x8*)&sP[wave][1][c][4 * g];
        __builtin_amdgcn_s_setprio(1);
#pragma unroll
        for (int dt = 0; dt < 4; ++dt) {
          bf16x8 bv = lds_frag(Vt, dt * 16 + c, ks * 64 + 16 * g);
          o[0][dt] = __builtin_amdgcn_mfma_f32_16x16x32_bf16(ap0, bv, o[0][dt], 0, 0, 0);
          o[1][dt] = __builtin_amdgcn_mfma_f32_16x16x32_bf16(ap1, bv, o[1][dt], 0, 0, 0);
        }
        __builtin_amdgcn_s_setprio(0);
      }
      __syncthreads();
    }

    lc0 += __shfl_xor(lc0, 16); lc0 += __shfl_xor(lc0, 32);
    lc1 += __shfl_xor(lc1, 16); lc1 += __shfl_xor(lc1, 32);
    int gi = chunk * 8 + bh;
    if (g == 0) {
      Gl[(size_t)gi * MPOS + i0 + c] = lc0;
      Gl[(size_t)gi * MPOS + i0 + 16 + c] = lc1;
    }
    float* gp = Gc + ((size_t)gi * MPOS + i0) * 64;
#pragma unroll
    for (int f = 0; f < 2; ++f)
#pragma unroll
      for (int dt = 0; dt < 4; ++dt)
#pragma unroll
        for (int r = 0; r < 4; ++r)
          gp[(size_t)(f * 16 + 4 * g + r) * 64 + dt * 16 + c] = o[f][dt][r];
  }
}

// ================= FUSED POST: dwb (blocks [0,3456)) + map_out (rest) ======
__global__ __launch_bounds__(256) void k_post(const unsigned short* __restrict__ F,
                                              const float* __restrict__ fout_dw,
                                              unsigned short* __restrict__ dwt2,
                                              const float* __restrict__ Gc,
                                              const float* __restrict__ Gl,
                                              const float* __restrict__ mow,
                                              float* __restrict__ out2) {
  int bid = blockIdx.x;
  int t = threadIdx.x;
  if (bid < 3456) {
    int tid = bid * 256 + t;
    int bc = tid / 1728;
    int s = tid - bc * 1728;
    int c = bc & (INNER - 1), b = bc / INNER;
    int cm = (c & 63) * 4 + (c >> 6);
    int xs = (s % 3) * 8;
    int row = s / 3;
    int y = row % 24, z = row / 24;
    const float* wr = fout_dw + cm * 27;
    const unsigned short* ip = F + (size_t)bc * NPOS;

    float w0a[9], w1a[9], w2a[9];
    int ro[9];
#pragma unroll
    for (int dz = 0; dz < 3; ++dz)
#pragma unroll
      for (int dy = 0; dy < 3; ++dy) {
        int r = dz * 3 + dy;
        int zz = z + dz - 1, yy = y + dy - 1;
        bool ok = ((unsigned)zz < 24u) && ((unsigned)yy < 24u);
        w0a[r] = ok ? wr[dz * 9 + dy * 3 + 0] : 0.f;
        w1a[r] = ok ? wr[dz * 9 + dy * 3 + 1] : 0.f;
        w2a[r] = ok ? wr[dz * 9 + dy * 3 + 2] : 0.f;
        int zc = min(max(zz, 0), 23), yc = min(max(yy, 0), 23);
        ro[r] = (zc * 24 + yc) * 24;
      }
    uint2 Bu[9], Cu[9];
    unsigned short m1[9], p8[9];
#pragma unroll
    for (int r = 0; r < 9; ++r) {
      Bu[r] = *(const uint2*)(ip + ro[r] + xs);
      Cu[r] = *(const uint2*)(ip + ro[r] + xs + 4);
      m1[r] = xs ? ip[ro[r] + xs - 1] : 0;
      p8[r] = (xs < 16) ? ip[ro[r] + xs + 8] : 0;
    }
    float acc[8];
#pragma unroll
    for (int i = 0; i < 8; ++i) acc[i] = 0.f;
#pragma unroll
    for (int r = 0; r < 9; ++r) {
      float xv[10];
      xv[0] = bf2f(m1[r]);
      xv[1] = __builtin_bit_cast(float, (Bu[r].x & 0xFFFFu) << 16);
      xv[2] = __builtin_bit_cast(float, Bu[r].x & 0xFFFF0000u);
      xv[3] = __builtin_bit_cast(float, (Bu[r].y & 0xFFFFu) << 16);
      xv[4] = __builtin_bit_cast(float, Bu[r].y & 0xFFFF0000u);
      xv[5] = __builtin_bit_cast(float, (Cu[r].x & 0xFFFFu) << 16);
      xv[6] = __builtin_bit_cast(float, Cu[r].x & 0xFFFF0000u);
      xv[7] = __builtin_bit_cast(float, (Cu[r].y & 0xFFFFu) << 16);
      xv[8] = __builtin_bit_cast(float, Cu[r].y & 0xFFFF0000u);
      xv[9] = bf2f(p8[r]);
#pragma unroll
      for (int i = 0; i < 8; ++i)
        acc[i] += w0a[r] * xv[i] + w1a[r] * xv[i + 1] + w2a[r] * xv[i + 2];
    }
    unsigned short* op = dwt2 + ((size_t)b * INNER + cm) * NPOS + row * 24 + xs;
    uint4 pv;
    pv.x = pk_bf16(acc[0], acc[1]);
    pv.y = pk_bf16(acc[2], acc[3]);
    pv.z = pk_bf16(acc[4], acc[5]);
    pv.w = pk_bf16(acc[6], acc[7]);
    *(uint4*)op = pv;
  } else {
    int mi = bid - 3456;
    int m = mi & 511, b = mi >> 9;
    __shared__ float sMA[256];
    __shared__ float sL2[4];
    if (t < 4) {
      float l = 0.f;
#pragma unroll 4
      for (int ch = 0; ch < JSPLIT; ++ch)
        l += Gl[(size_t)(ch * 8 + b * 4 + t) * MPOS + m];
      sL2[t] = 1.f / l;
    }
    __syncthreads();
    {
      int head = t & 3, dh = t >> 2;
      int bh = b * 4 + head;
      float a = 0.f;
#pragma unroll 4
      for (int ch = 0; ch < JSPLIT; ++ch)
        a += Gc[((size_t)(ch * 8 + bh) * MPOS + m) * 64 + dh];
      sMA[t] = a * sL2[head];
    }
    __syncthreads();
    if (t < 64) {
      const float* wr = mow + t * 256;
      float acc = 0.f;
#pragma unroll 4
      for (int c = 0; c < 256; ++c) acc += wr[c] * sMA[c];
      out2[((size_t)b * 64 + t) * MPOS + m] = acc;
    }
  }
}

// ---------------- MFMA pointwise out GEMM (fused in-LDS transpose) --------
__global__ __launch_bounds__(256) void k_pwout_m(const unsigned short* __restrict__ dwo,
                                                 const float* __restrict__ pw,
                                                 float* __restrict__ out1) {
  __shared__ __align__(16) char sW[32768];
  __shared__ __align__(16) char sB[32768];
  __shared__ __align__(16) char sR[16384];
  int t = threadIdx.x, wave = t >> 6, lane = t & 63, g = lane >> 4, c = lane & 15;
  int n0 = blockIdx.x * 128, ti = blockIdx.y, b = blockIdx.z;

  {
    int r = t >> 2, ks = (t & 3) * 64;
    const float* wp = pw + (size_t)(ti * 64 + r) * 256 + ks;
    unsigned pkv[32];
#pragma unroll
    for (int i = 0; i < 16; ++i) {
      float4 v = *(const float4*)(wp + i * 4);
      pkv[2 * i] = pk_bf16(v.x, v.y);
      pkv[2 * i + 1] = pk_bf16(v.z, v.w);
    }
#pragma unroll
    for (int u = 0; u < 8; ++u) {
      int colb = (ks * 2 + u * 16) ^ ((r & 7) << 4);
      *(uint4*)(sW + r * 512 + colb) = *(uint4*)&pkv[u * 4];
    }
  }

  f32x4 acc[4][2];
#pragma unroll
  for (int ct = 0; ct < 4; ++ct)
#pragma unroll
    for (int jf = 0; jf < 2; ++jf) acc[ct][jf] = (f32x4){0.f, 0.f, 0.f, 0.f};
  int nw = wave * 32;
  const char* Bgc = (const char*)(dwo + (size_t)b * INNER * NPOS);
  const unsigned short* R16 = (const unsigned short*)sR;

  for (int kh = 0; kh < 2; ++kh) {
#pragma unroll
    for (int q = 0; q < 2; ++q) {
#pragma unroll
      for (int p = 0; p < 4; ++p) {
        int oo = p * 4096 + t * 16;
        int kl = oo >> 8, col = oo & 255;
        GL2LDS(Bgc + (size_t)(kh * 128 + q * 64 + kl) * (NPOS * 2) + n0 * 2 + col,
               sR + oo);
      }
      __syncthreads();
#pragma unroll
      for (int it = 0; it < 4; ++it) {
        int cid = it * 256 + t;
        int n = cid & 127, kcl = (cid >> 7) & 7;
        unsigned short v[8];
#pragma unroll
        for (int j = 0; j < 8; ++j) v[j] = R16[(kcl * 8 + j) * 128 + n];
        unsigned u4[4];
#pragma unroll
        for (int i = 0; i < 4; ++i)
          u4[i] = (unsigned)v[2 * i] | ((unsigned)v[2 * i + 1] << 16);
        int kc16 = q * 8 + kcl;
        *(uint4*)(sB + n * 256 + ((kc16 * 16) ^ ((n & 7) << 4))) = *(uint4*)&u4[0];
      }
      __syncthreads();
    }
#pragma unroll
    for (int kc = 0; kc < 4; ++kc) {
      bf16x8 bq[2];
#pragma unroll
      for (int jf = 0; jf < 2; ++jf)
        bq[jf] = lds_fragP(sB, nw + jf * 16 + c, kc * 64 + g * 16, 256);
#pragma unroll
      for (int ct = 0; ct < 4; ++ct) {
        bf16x8 a = lds_fragP(sW, ct * 16 + c, (kh * 4 + kc) * 64 + g * 16, 512);
#pragma unroll
        for (int jf = 0; jf < 2; ++jf)
          acc[ct][jf] = __builtin_amdgcn_mfma_f32_16x16x32_bf16(a, bq[jf], acc[ct][jf], 0, 0, 0);
      }
    }
    __syncthreads();
  }
#pragma unroll
  for (int ct = 0; ct < 4; ++ct)
#pragma unroll
    for (int jf = 0; jf < 2; ++jf) {
      int n = n0 + nw + jf * 16 + c;
#pragma unroll
      for (int r = 0; r < 4; ++r) {
        int co = ti * 64 + ct * 16 + 4 * g + r;
        out1[((size_t)b * 128 + co) * NPOS + n] = acc[ct][jf][r];
      }
    }
}

extern "C" void kernel_launch(void* const* d_in, const int* in_sizes, int n_in,
                              void* d_out, int out_size, void* d_ws, size_t ws_size,
                              hipStream_t stream) {
  const float* feat = (const float*)d_in[0];
  const float* smap = (const float*)d_in[1];
  const float* fqv_dw = (const float*)d_in[2];
  const float* fqv_pw = (const float*)d_in[3];
  const float* fout_dw = (const float*)d_in[4];
  const float* fout_pw = (const float*)d_in[5];
  const float* mqv_w = (const float*)d_in[6];
  const float* mout_w = (const float*)d_in[7];

  float* out = (float*)d_out;
  float* out1 = out;                              // [2,128,24,24,24]
  float* out2 = out + (size_t)BB * 128 * NPOS;    // [2,64,8,8,8]

  const size_t QV = (size_t)BB * HEADS * NPOS * DH;   // 7,077,888
  const size_t MQV = (size_t)BB * HEADS * MPOS * DH;  // 262,144
  float* ws = (float*)d_ws;
  unsigned short* F = (unsigned short*)ws;             // bf16 attn row output
  unsigned short* fqb = (unsigned short*)(ws + QV);    // bf16 [bh][j][d]
  unsigned short* fvTb = fqb + QV;                     // bf16 [bh][d][j]
  unsigned short* mapqb = fvTb + QV;                   // bf16 [bh][i][d] (scaled)
  unsigned short* mapvTb = mapqb + MQV;                // bf16 [bh][d][i]
  float* Gc = (float*)(mapvTb + MQV);                  // [JSPLIT*8][512][64]
  float* Gl = Gc + (size_t)JSPLIT * 8 * MPOS * 64;     // [JSPLIT*8][512]

  // lifetime-disjoint aliases
  unsigned short* dwt = (unsigned short*)out1;  // dw1 out bf16; dead after pwqv
  unsigned short* dwt2 = fqb;                   // dw2 out bf16; fq dead after attn

  k_pre<<<dim3(1024 + BB * CH_FEAT * 1728 / 256), dim3(256), 0, stream>>>(
      smap, mqv_w, mapqb, mapvTb, feat, fqv_dw, dwt);
  k_pwqv_m<<<dim3(NPOS / 128, 8, BB), dim3(256), 0, stream>>>(dwt, fqv_pw, fqb, fvTb);
  k_attn<<<dim3(432 + 8 * 2 * JSPLIT), dim3(512), 0, stream>>>(
      fqb, fvTb, mapqb, mapvTb, F, Gc, Gl);
  k_post<<<dim3(BB * INNER * 1728 / 256 + BB * MPOS), dim3(256), 0, stream>>>(
      F, fout_dw, dwt2, Gc, Gl, mout_w, out2);
  k_pwout_m<<<dim3(NPOS / 128, 2, BB), dim3(256), 0, stream>>>(dwt2, fout_pw, out1);
}

// Round 18
// 176.876 us; speedup vs baseline: 1.0742x; 1.0742x over previous
//
#include <hip/hip_runtime.h>

#define BB 2
#define CH_FEAT 128
#define HEADS 4
#define DH 64
#define INNER 256
#define NPOS 13824   // 24^3
#define MPOS 512     // 8^3
#define DSZ 24
#define JSPLIT 27    // col-pass j chunks (432 col blocks, uniform with row blocks)
#define JCHUNK (NPOS / JSPLIT)  // 512
#define QSCALE (0.125f * 1.44269504088896340736f)  // fold 1/ln2: exp(s)=exp2(s')

typedef __attribute__((ext_vector_type(8))) short bf16x8;
typedef __attribute__((ext_vector_type(4))) float f32x4;

__device__ inline unsigned short bf16_rn(float x) {
  unsigned u = __builtin_bit_cast(unsigned, x);
  u += 0x7FFF + ((u >> 16) & 1);
  return (unsigned short)(u >> 16);
}
__device__ inline unsigned pk_bf16(float a, float b) {
  return (unsigned)bf16_rn(a) | ((unsigned)bf16_rn(b) << 16);
}
__device__ inline float bf2f(unsigned short u) {
  return __builtin_bit_cast(float, (unsigned)u << 16);
}

// async global->LDS 16B (dest must be wave-uniform base + lane*16)
#define GL2LDS(g, l)                                                        \
  __builtin_amdgcn_global_load_lds(                                         \
      (const __attribute__((address_space(1))) void*)(g),                   \
      (__attribute__((address_space(3))) void*)(l), 16, 0, 0)

// swizzled read of a 16B fragment from a [rows][pitch B] LDS tile
__device__ inline bf16x8 lds_frag(const char* tile, int row, int colb) {
  return *(const bf16x8*)(tile + row * 128 + (colb ^ ((row & 7) << 4)));
}
__device__ inline bf16x8 lds_fragP(const char* tile, int row, int colb, int pitch) {
  return *(const bf16x8*)(tile + row * pitch + (colb ^ ((row & 7) << 4)));
}

// ================= FUSED PRE: map_qv (blocks [0,1024)) + dwf (rest) ========
__global__ __launch_bounds__(256) void k_pre(const float* __restrict__ smap,
                                             const float* __restrict__ mqv_w,
                                             unsigned short* __restrict__ mapqb,
                                             unsigned short* __restrict__ mapvTb,
                                             const float* __restrict__ feat,
                                             const float* __restrict__ fqv_dw,
                                             unsigned short* __restrict__ dwt) {
  int bid = blockIdx.x;
  int t = threadIdx.x;
  if (bid < 1024) {
    int b = bid >> 9, m = bid & 511;
    __shared__ float s[64];
    if (t < 64) s[t] = smap[(size_t)(b * 64 + t) * MPOS + m];
    __syncthreads();
#pragma unroll
    for (int half = 0; half < 2; ++half) {
      int co2 = half * 256 + t;
      const float* wr = mqv_w + (size_t)co2 * 64;
      float acc = 0.f;
#pragma unroll
      for (int c = 0; c < 64; ++c) acc += wr[c] * s[c];
      int qv = co2 >> 8, c2 = co2 & 255, head = c2 & 3, dh = c2 >> 2;
      int bh = b * HEADS + head;
      if (qv == 0)
        mapqb[((size_t)bh * MPOS + m) * 64 + dh] = bf16_rn(acc * QSCALE);
      else
        mapvTb[((size_t)bh * 64 + dh) * MPOS + m] = bf16_rn(acc);
    }
  } else {
    int tid = (bid - 1024) * 256 + t;
    int bc = tid / 1728;
    int s = tid - bc * 1728;
    int c = bc & (CH_FEAT - 1);
    int xs = (s % 3) * 8;
    int row = s / 3;
    int y = row % 24, z = row / 24;
    const float* wr = fqv_dw + c * 27;
    const float* ip = feat + (size_t)bc * NPOS;

    float w0a[9], w1a[9], w2a[9];
    int ro[9];
#pragma unroll
    for (int dz = 0; dz < 3; ++dz)
#pragma unroll
      for (int dy = 0; dy < 3; ++dy) {
        int r = dz * 3 + dy;
        int zz = z + dz - 1, yy = y + dy - 1;
        bool ok = ((unsigned)zz < 24u) && ((unsigned)yy < 24u);
        w0a[r] = ok ? wr[dz * 9 + dy * 3 + 0] : 0.f;
        w1a[r] = ok ? wr[dz * 9 + dy * 3 + 1] : 0.f;
        w2a[r] = ok ? wr[dz * 9 + dy * 3 + 2] : 0.f;
        int zc = min(max(zz, 0), 23), yc = min(max(yy, 0), 23);
        ro[r] = (zc * 24 + yc) * 24;
      }
    float4 Bv[9], Cv[9];
    float xm1[9], x8[9];
#pragma unroll
    for (int r = 0; r < 9; ++r) {
      Bv[r] = *(const float4*)(ip + ro[r] + xs);
      Cv[r] = *(const float4*)(ip + ro[r] + xs + 4);
      xm1[r] = xs ? *(ip + ro[r] + xs - 1) : 0.f;
      x8[r] = (xs < 16) ? *(ip + ro[r] + xs + 8) : 0.f;
    }
    float acc[8];
#pragma unroll
    for (int i = 0; i < 8; ++i) acc[i] = 0.f;
#pragma unroll
    for (int r = 0; r < 9; ++r) {
      float xv[10] = {xm1[r], Bv[r].x, Bv[r].y, Bv[r].z, Bv[r].w,
                      Cv[r].x, Cv[r].y, Cv[r].z, Cv[r].w, x8[r]};
#pragma unroll
      for (int i = 0; i < 8; ++i)
        acc[i] += w0a[r] * xv[i] + w1a[r] * xv[i + 1] + w2a[r] * xv[i + 2];
    }
    unsigned short* op = dwt + (size_t)bc * NPOS + row * 24 + xs;
    uint4 pv;
    pv.x = pk_bf16(acc[0], acc[1]);
    pv.y = pk_bf16(acc[2], acc[3]);
    pv.z = pk_bf16(acc[4], acc[5]);
    pv.w = pk_bf16(acc[6], acc[7]);
    *(uint4*)op = pv;
  }
}

// ---------------- MFMA pointwise qv GEMM (fused in-LDS transpose) ---------
__global__ __launch_bounds__(256) void k_pwqv_m(const unsigned short* __restrict__ dwt,
                                                const float* __restrict__ pw,
                                                unsigned short* __restrict__ fqb,
                                                unsigned short* __restrict__ fvTb) {
  __shared__ __align__(16) char sW[16384];
  __shared__ __align__(16) char sR[32768];
  __shared__ __align__(16) char sB[32768];
  int t = threadIdx.x, wave = t >> 6, lane = t & 63, g = lane >> 4, c = lane & 15;
  int n0 = blockIdx.x * 128, ti = blockIdx.y, b = blockIdx.z;
  int qv = ti >> 2, head = ti & 3, bh = b * 4 + head;

  {
    int r = t >> 2, ks = (t & 3) * 32;
    int co = qv * 256 + r * 4 + head;
    const float* wp = pw + (size_t)co * 128 + ks;
    unsigned pkv[16];
#pragma unroll
    for (int i = 0; i < 8; ++i) {
      float4 v = *(const float4*)(wp + i * 4);
      pkv[2 * i] = pk_bf16(v.x, v.y);
      pkv[2 * i + 1] = pk_bf16(v.z, v.w);
    }
#pragma unroll
    for (int u = 0; u < 4; ++u) {
      int colb = (ks * 2 + u * 16) ^ ((r & 7) << 4);
      *(uint4*)(sW + r * 256 + colb) = *(uint4*)&pkv[u * 4];
    }
  }
  const char* Bgc = (const char*)(dwt + (size_t)b * CH_FEAT * NPOS);
#pragma unroll
  for (int p = 0; p < 8; ++p) {
    int oo = p * 4096 + t * 16;
    int k = oo >> 8, col = oo & 255;
    GL2LDS(Bgc + (size_t)k * (NPOS * 2) + n0 * 2 + col, sR + oo);
  }
  __syncthreads();

  {
    const unsigned short* R16 = (const unsigned short*)sR;
#pragma unroll
    for (int it = 0; it < 8; ++it) {
      int cid = it * 256 + t;
      int n = cid & 127, kc16 = (cid >> 7) & 15;
      unsigned short v[8];
#pragma unroll
      for (int j = 0; j < 8; ++j) v[j] = R16[(kc16 * 8 + j) * 128 + n];
      unsigned u4[4];
#pragma unroll
      for (int i = 0; i < 4; ++i)
        u4[i] = (unsigned)v[2 * i] | ((unsigned)v[2 * i + 1] << 16);
      *(uint4*)(sB + n * 256 + ((kc16 * 16) ^ ((n & 7) << 4))) = *(uint4*)&u4[0];
    }
  }
  __syncthreads();

  f32x4 acc[4][2];
#pragma unroll
  for (int ct = 0; ct < 4; ++ct)
#pragma unroll
    for (int jf = 0; jf < 2; ++jf) acc[ct][jf] = (f32x4){0.f, 0.f, 0.f, 0.f};
  int nw = wave * 32;
#pragma unroll
  for (int kc = 0; kc < 4; ++kc) {
    bf16x8 bq[2];
#pragma unroll
    for (int jf = 0; jf < 2; ++jf)
      bq[jf] = lds_fragP(sB, nw + jf * 16 + c, kc * 64 + g * 16, 256);
#pragma unroll
    for (int ct = 0; ct < 4; ++ct) {
      bf16x8 a = lds_fragP(sW, ct * 16 + c, kc * 64 + g * 16, 256);
#pragma unroll
      for (int jf = 0; jf < 2; ++jf)
        acc[ct][jf] = __builtin_amdgcn_mfma_f32_16x16x32_bf16(a, bq[jf], acc[ct][jf], 0, 0, 0);
    }
  }
  __syncthreads();

  char* dmp = sR;
#pragma unroll
  for (int ct = 0; ct < 4; ++ct)
#pragma unroll
    for (int jf = 0; jf < 2; ++jf) {
      int n = nw + jf * 16 + c;
      uint2 wv;
      wv.x = pk_bf16(acc[ct][jf][0], acc[ct][jf][1]);
      wv.y = pk_bf16(acc[ct][jf][2], acc[ct][jf][3]);
      *(uint2*)(dmp + n * 144 + (ct * 16 + 4 * g) * 2) = wv;
    }
  __syncthreads();

  if (qv == 0) {
    int nr = t >> 1, seg = t & 1;
    const char* src = dmp + nr * 144 + seg * 64;
    unsigned short* dst = fqb + ((size_t)bh * NPOS + n0 + nr) * 64 + seg * 32;
#pragma unroll
    for (int i = 0; i < 4; ++i)
      *(uint4*)(dst + i * 8) = *(const uint4*)(src + i * 16);
  } else {
#pragma unroll
    for (int it = 0; it < 2; ++it) {
      int idx = it * 256 + t;
      int dh = idx >> 3, nseg = (idx & 7) * 16;
      unsigned pkv[8];
#pragma unroll
      for (int i = 0; i < 8; ++i) {
        unsigned short lo = *(const unsigned short*)(dmp + (nseg + 2 * i) * 144 + dh * 2);
        unsigned short hi = *(const unsigned short*)(dmp + (nseg + 2 * i + 1) * 144 + dh * 2);
        pkv[i] = (unsigned)lo | ((unsigned)hi << 16);
      }
      unsigned short* dst = fvTb + ((size_t)bh * 64 + dh) * NPOS + n0 + nseg;
      *(uint4*)(dst) = *(uint4*)&pkv[0];
      *(uint4*)(dst + 8) = *(uint4*)&pkv[4];
    }
  }
}

// ================= FUSED ATTENTION (512 threads, 8 waves) ==================
// round-16 schedule + exp2 softmax; row [0,432), col [432,864)
__global__ __launch_bounds__(512, 4) void k_attn(const unsigned short* __restrict__ fqb,
                                                 const unsigned short* __restrict__ fvTb,
                                                 const unsigned short* __restrict__ mapqb,
                                                 const unsigned short* __restrict__ mapvTb,
                                                 unsigned short* __restrict__ F,
                                                 float* __restrict__ Gc,
                                                 float* __restrict__ Gl) {
  __shared__ __align__(16) char sAll[70656];  // [0,32K) dbuf | sP | sL
  char* sPool = sAll;
  unsigned (*sP)[2][16][36] = (unsigned (*)[2][16][36])(sAll + 32768);
  float (*sL)[2][16] = (float (*)[2][16])(sAll + 32768 + 36864);
  int bid = blockIdx.x;
  int t = threadIdx.x, wave = t >> 6, lane = t & 63, g = lane >> 4, c = lane & 15;

  if (bid < 432) {  // ========== ROW PASS ==========
    int jblk = bid % 54, bh = bid / 54;
    int j0 = jblk * 256 + wave * 32;

    const char* Kg = (const char*)(mapqb + (size_t)bh * MPOS * 64);
    const char* Vg = (const char*)(mapvTb + (size_t)bh * 64 * MPOS);

    const unsigned short* fqp = fqb + ((size_t)bh * NPOS + j0 + c) * 64 + 8 * g;
    bf16x8 bq00 = *(const bf16x8*)(fqp);
    bf16x8 bq01 = *(const bf16x8*)(fqp + 32);
    bf16x8 bq10 = *(const bf16x8*)(fqp + 16 * 64);
    bf16x8 bq11 = *(const bf16x8*)(fqp + 16 * 64 + 32);

    f32x4 o[2][4];
#pragma unroll
    for (int jf = 0; jf < 2; ++jf)
#pragma unroll
      for (int dt = 0; dt < 4; ++dt) o[jf][dt] = (f32x4){0.f, 0.f, 0.f, 0.f};
    float ls0 = 0.f, ls1 = 0.f;

    {
      int oo = t * 16;
      int row = oo >> 7, col = (oo & 127) ^ (((oo >> 7) & 7) << 4);
      GL2LDS(Kg + (size_t)row * 128 + col, sPool + oo);
      GL2LDS(Vg + (size_t)row * 1024 + col, sPool + 16384 + oo);
    }
    __syncthreads();

    for (int ic = 0; ic < 8; ++ic) {
      const char* Kt = sPool + (ic & 1) * 8192;
      const char* Vt = sPool + 16384 + (ic & 1) * 8192;
      if (ic < 7) {
        int ibase = (ic + 1) * 64;
        int bsel = ((ic + 1) & 1) * 8192;
        int oo = t * 16;
        int row = oo >> 7, col = (oo & 127) ^ (((oo >> 7) & 7) << 4);
        GL2LDS(Kg + (size_t)(ibase + row) * 128 + col, sPool + bsel + oo);
        GL2LDS(Vg + (size_t)row * 1024 + ibase * 2 + col, sPool + 16384 + bsel + oo);
      }
#pragma unroll
      for (int ti = 0; ti < 4; ++ti) {
        bf16x8 a0 = lds_frag(Kt, ti * 16 + c, 16 * g);
        bf16x8 a1 = lds_frag(Kt, ti * 16 + c, 64 + 16 * g);
        f32x4 s0 = {0.f, 0.f, 0.f, 0.f}, s1 = {0.f, 0.f, 0.f, 0.f};
        s0 = __builtin_amdgcn_mfma_f32_16x16x32_bf16(a0, bq00, s0, 0, 0, 0);
        s0 = __builtin_amdgcn_mfma_f32_16x16x32_bf16(a1, bq01, s0, 0, 0, 0);
        s1 = __builtin_amdgcn_mfma_f32_16x16x32_bf16(a0, bq10, s1, 0, 0, 0);
        s1 = __builtin_amdgcn_mfma_f32_16x16x32_bf16(a1, bq11, s1, 0, 0, 0);
        float p0 = __builtin_amdgcn_exp2f(s0[0]), p1 = __builtin_amdgcn_exp2f(s0[1]);
        float p2 = __builtin_amdgcn_exp2f(s0[2]), p3 = __builtin_amdgcn_exp2f(s0[3]);
        ls0 += (p0 + p1) + (p2 + p3);
        sP[wave][0][c][ti * 8 + 2 * g] = pk_bf16(p0, p1);
        sP[wave][0][c][ti * 8 + 2 * g + 1] = pk_bf16(p2, p3);
        float q0 = __builtin_amdgcn_exp2f(s1[0]), q1 = __builtin_amdgcn_exp2f(s1[1]);
        float q2 = __builtin_amdgcn_exp2f(s1[2]), q3 = __builtin_amdgcn_exp2f(s1[3]);
        ls1 += (q0 + q1) + (q2 + q3);
        sP[wave][1][c][ti * 8 + 2 * g] = pk_bf16(q0, q1);
        sP[wave][1][c][ti * 8 + 2 * g + 1] = pk_bf16(q2, q3);
      }
#pragma unroll
      for (int ks = 0; ks < 2; ++ks) {
        bf16x8 ap0 = *(const bf16x8*)&sP[wave][0][c][ks * 16 + 4 * g];
        bf16x8 ap1 = *(const bf16x8*)&sP[wave][1][c][ks * 16 + 4 * g];
#pragma unroll
        for (int dt = 0; dt < 4; ++dt) {
          bf16x8 bv = lds_frag(Vt, dt * 16 + c, ks * 64 + 16 * g);
          o[0][dt] = __builtin_amdgcn_mfma_f32_16x16x32_bf16(ap0, bv, o[0][dt], 0, 0, 0);
          o[1][dt] = __builtin_amdgcn_mfma_f32_16x16x32_bf16(ap1, bv, o[1][dt], 0, 0, 0);
        }
      }
      __syncthreads();
    }

    ls0 += __shfl_xor(ls0, 16); ls0 += __shfl_xor(ls0, 32);
    ls1 += __shfl_xor(ls1, 16); ls1 += __shfl_xor(ls1, 32);
    if (g == 0) { sL[wave][0][c] = 1.f / ls0; sL[wave][1][c] = 1.f / ls1; }
#pragma unroll
    for (int jf = 0; jf < 2; ++jf) {
      float rl0 = sL[wave][jf][4 * g + 0], rl1 = sL[wave][jf][4 * g + 1];
      float rl2 = sL[wave][jf][4 * g + 2], rl3 = sL[wave][jf][4 * g + 3];
#pragma unroll
      for (int dt = 0; dt < 4; ++dt) {
        uint2 wv;
        wv.x = pk_bf16(o[jf][dt][0] * rl0, o[jf][dt][1] * rl1);
        wv.y = pk_bf16(o[jf][dt][2] * rl2, o[jf][dt][3] * rl3);
        *(uint2*)(sAll + (dt * 16 + c) * 544 + (wave * 32 + jf * 16 + 4 * g) * 2) = wv;
      }
    }
    __syncthreads();
    {
      int ch = t >> 3, seg = t & 7;
      int b = bh >> 2, head = bh & 3;
      unsigned short* dst = F + ((size_t)b * INNER + head * 64 + ch) * NPOS +
                            jblk * 256 + seg * 32;
      const char* src = sAll + ch * 544 + seg * 64;
#pragma unroll
      for (int i = 0; i < 4; ++i)
        *(uint4*)(dst + i * 8) = *(const uint4*)(src + i * 16);
    }
  } else {  // ========== COL PASS (bh-fastest for XCD pinning) ==========
    int cid = bid - 432;
    int bh = cid & 7, iblk = (cid >> 3) & 1, chunk = cid >> 4;
    char* sQ = sPool;
    char* sV = sPool + 16384;
    int i0 = iblk * 256 + wave * 32;
    int jb = chunk * JCHUNK;

    const char* Qg = (const char*)(fqb + (size_t)bh * NPOS * 64);
    const char* Vg = (const char*)(fvTb + (size_t)bh * 64 * NPOS);

    const unsigned short* kp = mapqb + ((size_t)bh * MPOS + i0 + c) * 64 + 8 * g;
    bf16x8 bm00 = *(const bf16x8*)(kp);
    bf16x8 bm01 = *(const bf16x8*)(kp + 32);
    bf16x8 bm10 = *(const bf16x8*)(kp + 16 * 64);
    bf16x8 bm11 = *(const bf16x8*)(kp + 16 * 64 + 32);

    f32x4 o[2][4];
#pragma unroll
    for (int f = 0; f < 2; ++f)
#pragma unroll
      for (int dt = 0; dt < 4; ++dt) o[f][dt] = (f32x4){0.f, 0.f, 0.f, 0.f};
    float lc0 = 0.f, lc1 = 0.f;

    {
      int oo = t * 16;
      int row = oo >> 7, col = (oo & 127) ^ (((oo >> 7) & 7) << 4);
      GL2LDS(Qg + (size_t)(jb + row) * 128 + col, sQ + oo);
      GL2LDS(Vg + (size_t)row * (NPOS * 2) + jb * 2 + col, sV + oo);
    }
    __syncthreads();

    for (int jc = 0; jc < JCHUNK / 64; ++jc) {
      const char* Qt = sQ + (jc & 1) * 8192;
      const char* Vt = sV + (jc & 1) * 8192;
      if (jc < JCHUNK / 64 - 1) {
        int jbase = jb + (jc + 1) * 64;
        int bsel = ((jc + 1) & 1) * 8192;
        int oo = t * 16;
        int row = oo >> 7, col = (oo & 127) ^ (((oo >> 7) & 7) << 4);
        GL2LDS(Qg + (size_t)(jbase + row) * 128 + col, sQ + bsel + oo);
        GL2LDS(Vg + (size_t)row * (NPOS * 2) + jbase * 2 + col, sV + bsel + oo);
      }
#pragma unroll
      for (int tj = 0; tj < 4; ++tj) {
        bf16x8 a0 = lds_frag(Qt, tj * 16 + c, 16 * g);
        bf16x8 a1 = lds_frag(Qt, tj * 16 + c, 64 + 16 * g);
        f32x4 s0 = {0.f, 0.f, 0.f, 0.f}, s1 = {0.f, 0.f, 0.f, 0.f};
        s0 = __builtin_amdgcn_mfma_f32_16x16x32_bf16(a0, bm00, s0, 0, 0, 0);
        s0 = __builtin_amdgcn_mfma_f32_16x16x32_bf16(a1, bm01, s0, 0, 0, 0);
        s1 = __builtin_amdgcn_mfma_f32_16x16x32_bf16(a0, bm10, s1, 0, 0, 0);
        s1 = __builtin_amdgcn_mfma_f32_16x16x32_bf16(a1, bm11, s1, 0, 0, 0);
        float p0 = __builtin_amdgcn_exp2f(s0[0]), p1 = __builtin_amdgcn_exp2f(s0[1]);
        float p2 = __builtin_amdgcn_exp2f(s0[2]), p3 = __builtin_amdgcn_exp2f(s0[3]);
        lc0 += (p0 + p1) + (p2 + p3);
        sP[wave][0][c][tj * 8 + 2 * g] = pk_bf16(p0, p1);
        sP[wave][0][c][tj * 8 + 2 * g + 1] = pk_bf16(p2, p3);
        float q0 = __builtin_amdgcn_exp2f(s1[0]), q1 = __builtin_amdgcn_exp2f(s1[1]);
        float q2 = __builtin_amdgcn_exp2f(s1[2]), q3 = __builtin_amdgcn_exp2f(s1[3]);
        lc1 += (q0 + q1) + (q2 + q3);
        sP[wave][1][c][tj * 8 + 2 * g] = pk_bf16(q0, q1);
        sP[wave][1][c][tj * 8 + 2 * g + 1] = pk_bf16(q2, q3);
      }
#pragma unroll
      for (int ks = 0; ks < 2; ++ks) {
        bf16x8 ap0 = *(const bf16x8*)&sP[wave][0][c][ks * 16 + 4 * g];
        bf16x8 ap1 = *(const bf16x8*)&sP[wave][1][c][ks * 16 + 4 * g];
#pragma unroll
        for (int dt = 0; dt < 4; ++dt) {
          bf16x8 bv = lds_frag(Vt, dt * 16 + c, ks * 64 + 16 * g);
          o[0][dt] = __builtin_amdgcn_mfma_f32_16x16x32_bf16(ap0, bv, o[0][dt], 0, 0, 0);
          o[1][dt] = __builtin_amdgcn_mfma_f32_16x16x32_bf16(ap1, bv, o[1][dt], 0, 0, 0);
        }
      }
      __syncthreads();
    }

    lc0 += __shfl_xor(lc0, 16); lc0 += __shfl_xor(lc0, 32);
    lc1 += __shfl_xor(lc1, 16); lc1 += __shfl_xor(lc1, 32);
    int gi = chunk * 8 + bh;
    if (g == 0) {
      Gl[(size_t)gi * MPOS + i0 + c] = lc0;
      Gl[(size_t)gi * MPOS + i0 + 16 + c] = lc1;
    }
    float* gp = Gc + ((size_t)gi * MPOS + i0) * 64;
#pragma unroll
    for (int f = 0; f < 2; ++f)
#pragma unroll
      for (int dt = 0; dt < 4; ++dt)
#pragma unroll
        for (int r = 0; r < 4; ++r)
          gp[(size_t)(f * 16 + 4 * g + r) * 64 + dt * 16 + c] = o[f][dt][r];
  }
}

// ================= FUSED POST: dwb (blocks [0,3456)) + map_out (rest) ======
__global__ __launch_bounds__(256) void k_post(const unsigned short* __restrict__ F,
                                              const float* __restrict__ fout_dw,
                                              unsigned short* __restrict__ dwt2,
                                              const float* __restrict__ Gc,
                                              const float* __restrict__ Gl,
                                              const float* __restrict__ mow,
                                              float* __restrict__ out2) {
  int bid = blockIdx.x;
  int t = threadIdx.x;
  if (bid < 3456) {
    int tid = bid * 256 + t;
    int bc = tid / 1728;
    int s = tid - bc * 1728;
    int c = bc & (INNER - 1), b = bc / INNER;
    int cm = (c & 63) * 4 + (c >> 6);
    int xs = (s % 3) * 8;
    int row = s / 3;
    int y = row % 24, z = row / 24;
    const float* wr = fout_dw + cm * 27;
    const unsigned short* ip = F + (size_t)bc * NPOS;

    float w0a[9], w1a[9], w2a[9];
    int ro[9];
#pragma unroll
    for (int dz = 0; dz < 3; ++dz)
#pragma unroll
      for (int dy = 0; dy < 3; ++dy) {
        int r = dz * 3 + dy;
        int zz = z + dz - 1, yy = y + dy - 1;
        bool ok = ((unsigned)zz < 24u) && ((unsigned)yy < 24u);
        w0a[r] = ok ? wr[dz * 9 + dy * 3 + 0] : 0.f;
        w1a[r] = ok ? wr[dz * 9 + dy * 3 + 1] : 0.f;
        w2a[r] = ok ? wr[dz * 9 + dy * 3 + 2] : 0.f;
        int zc = min(max(zz, 0), 23), yc = min(max(yy, 0), 23);
        ro[r] = (zc * 24 + yc) * 24;
      }
    uint2 Bu[9], Cu[9];
    unsigned short m1[9], p8[9];
#pragma unroll
    for (int r = 0; r < 9; ++r) {
      Bu[r] = *(const uint2*)(ip + ro[r] + xs);
      Cu[r] = *(const uint2*)(ip + ro[r] + xs + 4);
      m1[r] = xs ? ip[ro[r] + xs - 1] : 0;
      p8[r] = (xs < 16) ? ip[ro[r] + xs + 8] : 0;
    }
    float acc[8];
#pragma unroll
    for (int i = 0; i < 8; ++i) acc[i] = 0.f;
#pragma unroll
    for (int r = 0; r < 9; ++r) {
      float xv[10];
      xv[0] = bf2f(m1[r]);
      xv[1] = __builtin_bit_cast(float, (Bu[r].x & 0xFFFFu) << 16);
      xv[2] = __builtin_bit_cast(float, Bu[r].x & 0xFFFF0000u);
      xv[3] = __builtin_bit_cast(float, (Bu[r].y & 0xFFFFu) << 16);
      xv[4] = __builtin_bit_cast(float, Bu[r].y & 0xFFFF0000u);
      xv[5] = __builtin_bit_cast(float, (Cu[r].x & 0xFFFFu) << 16);
      xv[6] = __builtin_bit_cast(float, Cu[r].x & 0xFFFF0000u);
      xv[7] = __builtin_bit_cast(float, (Cu[r].y & 0xFFFFu) << 16);
      xv[8] = __builtin_bit_cast(float, Cu[r].y & 0xFFFF0000u);
      xv[9] = bf2f(p8[r]);
#pragma unroll
      for (int i = 0; i < 8; ++i)
        acc[i] += w0a[r] * xv[i] + w1a[r] * xv[i + 1] + w2a[r] * xv[i + 2];
    }
    unsigned short* op = dwt2 + ((size_t)b * INNER + cm) * NPOS + row * 24 + xs;
    uint4 pv;
    pv.x = pk_bf16(acc[0], acc[1]);
    pv.y = pk_bf16(acc[2], acc[3]);
    pv.z = pk_bf16(acc[4], acc[5]);
    pv.w = pk_bf16(acc[6], acc[7]);
    *(uint4*)op = pv;
  } else {
    int mi = bid - 3456;
    int m = mi & 511, b = mi >> 9;
    __shared__ float sMA[256];
    __shared__ float sL2[4];
    if (t < 4) {
      float l = 0.f;
#pragma unroll 4
      for (int ch = 0; ch < JSPLIT; ++ch)
        l += Gl[(size_t)(ch * 8 + b * 4 + t) * MPOS + m];
      sL2[t] = 1.f / l;
    }
    __syncthreads();
    {
      int head = t & 3, dh = t >> 2;
      int bh = b * 4 + head;
      float a = 0.f;
#pragma unroll 4
      for (int ch = 0; ch < JSPLIT; ++ch)
        a += Gc[((size_t)(ch * 8 + bh) * MPOS + m) * 64 + dh];
      sMA[t] = a * sL2[head];
    }
    __syncthreads();
    if (t < 64) {
      const float* wr = mow + t * 256;
      float acc = 0.f;
#pragma unroll 4
      for (int c = 0; c < 256; ++c) acc += wr[c] * sMA[c];
      out2[((size_t)b * 64 + t) * MPOS + m] = acc;
    }
  }
}

// ---------------- MFMA pointwise out GEMM (fused in-LDS transpose) --------
__global__ __launch_bounds__(256) void k_pwout_m(const unsigned short* __restrict__ dwo,
                                                 const float* __restrict__ pw,
                                                 float* __restrict__ out1) {
  __shared__ __align__(16) char sW[32768];
  __shared__ __align__(16) char sB[32768];
  __shared__ __align__(16) char sR[16384];
  int t = threadIdx.x, wave = t >> 6, lane = t & 63, g = lane >> 4, c = lane & 15;
  int n0 = blockIdx.x * 128, ti = blockIdx.y, b = blockIdx.z;

  {
    int r = t >> 2, ks = (t & 3) * 64;
    const float* wp = pw + (size_t)(ti * 64 + r) * 256 + ks;
    unsigned pkv[32];
#pragma unroll
    for (int i = 0; i < 16; ++i) {
      float4 v = *(const float4*)(wp + i * 4);
      pkv[2 * i] = pk_bf16(v.x, v.y);
      pkv[2 * i + 1] = pk_bf16(v.z, v.w);
    }
#pragma unroll
    for (int u = 0; u < 8; ++u) {
      int colb = (ks * 2 + u * 16) ^ ((r & 7) << 4);
      *(uint4*)(sW + r * 512 + colb) = *(uint4*)&pkv[u * 4];
    }
  }

  f32x4 acc[4][2];
#pragma unroll
  for (int ct = 0; ct < 4; ++ct)
#pragma unroll
    for (int jf = 0; jf < 2; ++jf) acc[ct][jf] = (f32x4){0.f, 0.f, 0.f, 0.f};
  int nw = wave * 32;
  const char* Bgc = (const char*)(dwo + (size_t)b * INNER * NPOS);
  const unsigned short* R16 = (const unsigned short*)sR;

  for (int kh = 0; kh < 2; ++kh) {
#pragma unroll
    for (int q = 0; q < 2; ++q) {
#pragma unroll
      for (int p = 0; p < 4; ++p) {
        int oo = p * 4096 + t * 16;
        int kl = oo >> 8, col = oo & 255;
        GL2LDS(Bgc + (size_t)(kh * 128 + q * 64 + kl) * (NPOS * 2) + n0 * 2 + col,
               sR + oo);
      }
      __syncthreads();
#pragma unroll
      for (int it = 0; it < 4; ++it) {
        int cid = it * 256 + t;
        int n = cid & 127, kcl = (cid >> 7) & 7;
        unsigned short v[8];
#pragma unroll
        for (int j = 0; j < 8; ++j) v[j] = R16[(kcl * 8 + j) * 128 + n];
        unsigned u4[4];
#pragma unroll
        for (int i = 0; i < 4; ++i)
          u4[i] = (unsigned)v[2 * i] | ((unsigned)v[2 * i + 1] << 16);
        int kc16 = q * 8 + kcl;
        *(uint4*)(sB + n * 256 + ((kc16 * 16) ^ ((n & 7) << 4))) = *(uint4*)&u4[0];
      }
      __syncthreads();
    }
#pragma unroll
    for (int kc = 0; kc < 4; ++kc) {
      bf16x8 bq[2];
#pragma unroll
      for (int jf = 0; jf < 2; ++jf)
        bq[jf] = lds_fragP(sB, nw + jf * 16 + c, kc * 64 + g * 16, 256);
#pragma unroll
      for (int ct = 0; ct < 4; ++ct) {
        bf16x8 a = lds_fragP(sW, ct * 16 + c, (kh * 4 + kc) * 64 + g * 16, 512);
#pragma unroll
        for (int jf = 0; jf < 2; ++jf)
          acc[ct][jf] = __builtin_amdgcn_mfma_f32_16x16x32_bf16(a, bq[jf], acc[ct][jf], 0, 0, 0);
      }
    }
    __syncthreads();
  }
#pragma unroll
  for (int ct = 0; ct < 4; ++ct)
#pragma unroll
    for (int jf = 0; jf < 2; ++jf) {
      int n = n0 + nw + jf * 16 + c;
#pragma unroll
      for (int r = 0; r < 4; ++r) {
        int co = ti * 64 + ct * 16 + 4 * g + r;
        out1[((size_t)b * 128 + co) * NPOS + n] = acc[ct][jf][r];
      }
    }
}

extern "C" void kernel_launch(void* const* d_in, const int* in_sizes, int n_in,
                              void* d_out, int out_size, void* d_ws, size_t ws_size,
                              hipStream_t stream) {
  const float* feat = (const float*)d_in[0];
  const float* smap = (const float*)d_in[1];
  const float* fqv_dw = (const float*)d_in[2];
  const float* fqv_pw = (const float*)d_in[3];
  const float* fout_dw = (const float*)d_in[4];
  const float* fout_pw = (const float*)d_in[5];
  const float* mqv_w = (const float*)d_in[6];
  const float* mout_w = (const float*)d_in[7];

  float* out = (float*)d_out;
  float* out1 = out;                              // [2,128,24,24,24]
  float* out2 = out + (size_t)BB * 128 * NPOS;    // [2,64,8,8,8]

  const size_t QV = (size_t)BB * HEADS * NPOS * DH;   // 7,077,888
  const size_t MQV = (size_t)BB * HEADS * MPOS * DH;  // 262,144
  float* ws = (float*)d_ws;
  unsigned short* F = (unsigned short*)ws;             // bf16 attn row output
  unsigned short* fqb = (unsigned short*)(ws + QV);    // bf16 [bh][j][d]
  unsigned short* fvTb = fqb + QV;                     // bf16 [bh][d][j]
  unsigned short* mapqb = fvTb + QV;                   // bf16 [bh][i][d] (scaled)
  unsigned short* mapvTb = mapqb + MQV;                // bf16 [bh][d][i]
  float* Gc = (float*)(mapvTb + MQV);                  // [JSPLIT*8][512][64]
  float* Gl = Gc + (size_t)JSPLIT * 8 * MPOS * 64;     // [JSPLIT*8][512]

  // lifetime-disjoint aliases
  unsigned short* dwt = (unsigned short*)out1;  // dw1 out bf16; dead after pwqv
  unsigned short* dwt2 = fqb;                   // dw2 out bf16; fq dead after attn

  k_pre<<<dim3(1024 + BB * CH_FEAT * 1728 / 256), dim3(256), 0, stream>>>(
      smap, mqv_w, mapqb, mapvTb, feat, fqv_dw, dwt);
  k_pwqv_m<<<dim3(NPOS / 128, 8, BB), dim3(256), 0, stream>>>(dwt, fqv_pw, fqb, fvTb);
  k_attn<<<dim3(432 + 8 * 2 * JSPLIT), dim3(512), 0, stream>>>(
      fqb, fvTb, mapqb, mapvTb, F, Gc, Gl);
  k_post<<<dim3(BB * INNER * 1728 / 256 + BB * MPOS), dim3(256), 0, stream>>>(
      F, fout_dw, dwt2, Gc, Gl, mout_w, out2);
  k_pwout_m<<<dim3(NPOS / 128, 2, BB), dim3(256), 0, stream>>>(dwt2, fout_pw, out1);
}

// Round 19
// 165.755 us; speedup vs baseline: 1.1462x; 1.0671x over previous
//
#include <hip/hip_runtime.h>

#define BB 2
#define CH_FEAT 128
#define HEADS 4
#define DH 64
#define INNER 256
#define NPOS 13824   // 24^3
#define MPOS 512     // 8^3
#define DSZ 24
#define JSPLIT 27    // col-pass j chunks (432 col blocks, uniform with row blocks)
#define JCHUNK (NPOS / JSPLIT)  // 512
#define QSCALE (0.125f * 1.44269504088896340736f)  // fold 1/ln2: exp(s)=exp2(s')

typedef __attribute__((ext_vector_type(8))) short bf16x8;
typedef __attribute__((ext_vector_type(4))) float f32x4;

__device__ inline unsigned short bf16_rn(float x) {
  unsigned u = __builtin_bit_cast(unsigned, x);
  u += 0x7FFF + ((u >> 16) & 1);
  return (unsigned short)(u >> 16);
}
__device__ inline unsigned pk_bf16(float a, float b) {
  return (unsigned)bf16_rn(a) | ((unsigned)bf16_rn(b) << 16);
}
__device__ inline float bf2f(unsigned short u) {
  return __builtin_bit_cast(float, (unsigned)u << 16);
}

// async global->LDS 16B (dest must be wave-uniform base + lane*16)
#define GL2LDS(g, l)                                                        \
  __builtin_amdgcn_global_load_lds(                                         \
      (const __attribute__((address_space(1))) void*)(g),                   \
      (__attribute__((address_space(3))) void*)(l), 16, 0, 0)

// swizzled read of a 16B fragment from a [rows][pitch B] LDS tile
__device__ inline bf16x8 lds_frag(const char* tile, int row, int colb) {
  return *(const bf16x8*)(tile + row * 128 + (colb ^ ((row & 7) << 4)));
}
__device__ inline bf16x8 lds_fragP(const char* tile, int row, int colb, int pitch) {
  return *(const bf16x8*)(tile + row * pitch + (colb ^ ((row & 7) << 4)));
}

// ================= FUSED PRE: map_qv (blocks [0,1024)) + dwf (rest) ========
__global__ __launch_bounds__(256) void k_pre(const float* __restrict__ smap,
                                             const float* __restrict__ mqv_w,
                                             unsigned short* __restrict__ mapqb,
                                             unsigned short* __restrict__ mapvTb,
                                             const float* __restrict__ feat,
                                             const float* __restrict__ fqv_dw,
                                             unsigned short* __restrict__ dwt) {
  int bid = blockIdx.x;
  int t = threadIdx.x;
  if (bid < 1024) {
    int b = bid >> 9, m = bid & 511;
    __shared__ float s[64];
    if (t < 64) s[t] = smap[(size_t)(b * 64 + t) * MPOS + m];
    __syncthreads();
#pragma unroll
    for (int half = 0; half < 2; ++half) {
      int co2 = half * 256 + t;
      const float* wr = mqv_w + (size_t)co2 * 64;
      float acc = 0.f;
#pragma unroll
      for (int c = 0; c < 64; ++c) acc += wr[c] * s[c];
      int qv = co2 >> 8, c2 = co2 & 255, head = c2 & 3, dh = c2 >> 2;
      int bh = b * HEADS + head;
      if (qv == 0)
        mapqb[((size_t)bh * MPOS + m) * 64 + dh] = bf16_rn(acc * QSCALE);
      else
        mapvTb[((size_t)bh * 64 + dh) * MPOS + m] = bf16_rn(acc);
    }
  } else {
    int tid = (bid - 1024) * 256 + t;
    int bc = tid / 1728;
    int s = tid - bc * 1728;
    int c = bc & (CH_FEAT - 1);
    int xs = (s % 3) * 8;
    int row = s / 3;
    int y = row % 24, z = row / 24;
    const float* wr = fqv_dw + c * 27;
    const float* ip = feat + (size_t)bc * NPOS;

    float w0a[9], w1a[9], w2a[9];
    int ro[9];
#pragma unroll
    for (int dz = 0; dz < 3; ++dz)
#pragma unroll
      for (int dy = 0; dy < 3; ++dy) {
        int r = dz * 3 + dy;
        int zz = z + dz - 1, yy = y + dy - 1;
        bool ok = ((unsigned)zz < 24u) && ((unsigned)yy < 24u);
        w0a[r] = ok ? wr[dz * 9 + dy * 3 + 0] : 0.f;
        w1a[r] = ok ? wr[dz * 9 + dy * 3 + 1] : 0.f;
        w2a[r] = ok ? wr[dz * 9 + dy * 3 + 2] : 0.f;
        int zc = min(max(zz, 0), 23), yc = min(max(yy, 0), 23);
        ro[r] = (zc * 24 + yc) * 24;
      }
    float4 Bv[9], Cv[9];
    float xm1[9], x8[9];
#pragma unroll
    for (int r = 0; r < 9; ++r) {
      Bv[r] = *(const float4*)(ip + ro[r] + xs);
      Cv[r] = *(const float4*)(ip + ro[r] + xs + 4);
      xm1[r] = xs ? *(ip + ro[r] + xs - 1) : 0.f;
      x8[r] = (xs < 16) ? *(ip + ro[r] + xs + 8) : 0.f;
    }
    float acc[8];
#pragma unroll
    for (int i = 0; i < 8; ++i) acc[i] = 0.f;
#pragma unroll
    for (int r = 0; r < 9; ++r) {
      float xv[10] = {xm1[r], Bv[r].x, Bv[r].y, Bv[r].z, Bv[r].w,
                      Cv[r].x, Cv[r].y, Cv[r].z, Cv[r].w, x8[r]};
#pragma unroll
      for (int i = 0; i < 8; ++i)
        acc[i] += w0a[r] * xv[i] + w1a[r] * xv[i + 1] + w2a[r] * xv[i + 2];
    }
    unsigned short* op = dwt + (size_t)bc * NPOS + row * 24 + xs;
    uint4 pv;
    pv.x = pk_bf16(acc[0], acc[1]);
    pv.y = pk_bf16(acc[2], acc[3]);
    pv.z = pk_bf16(acc[4], acc[5]);
    pv.w = pk_bf16(acc[6], acc[7]);
    *(uint4*)op = pv;
  }
}

// ---------------- MFMA pointwise qv GEMM (fused in-LDS transpose) ---------
__global__ __launch_bounds__(256) void k_pwqv_m(const unsigned short* __restrict__ dwt,
                                                const float* __restrict__ pw,
                                                unsigned short* __restrict__ fqb,
                                                unsigned short* __restrict__ fvTb) {
  __shared__ __align__(16) char sW[16384];
  __shared__ __align__(16) char sR[32768];
  __shared__ __align__(16) char sB[32768];
  int t = threadIdx.x, wave = t >> 6, lane = t & 63, g = lane >> 4, c = lane & 15;
  int n0 = blockIdx.x * 128, ti = blockIdx.y, b = blockIdx.z;
  int qv = ti >> 2, head = ti & 3, bh = b * 4 + head;

  {
    int r = t >> 2, ks = (t & 3) * 32;
    int co = qv * 256 + r * 4 + head;
    const float* wp = pw + (size_t)co * 128 + ks;
    unsigned pkv[16];
#pragma unroll
    for (int i = 0; i < 8; ++i) {
      float4 v = *(const float4*)(wp + i * 4);
      pkv[2 * i] = pk_bf16(v.x, v.y);
      pkv[2 * i + 1] = pk_bf16(v.z, v.w);
    }
#pragma unroll
    for (int u = 0; u < 4; ++u) {
      int colb = (ks * 2 + u * 16) ^ ((r & 7) << 4);
      *(uint4*)(sW + r * 256 + colb) = *(uint4*)&pkv[u * 4];
    }
  }
  const char* Bgc = (const char*)(dwt + (size_t)b * CH_FEAT * NPOS);
#pragma unroll
  for (int p = 0; p < 8; ++p) {
    int oo = p * 4096 + t * 16;
    int k = oo >> 8, col = oo & 255;
    GL2LDS(Bgc + (size_t)k * (NPOS * 2) + n0 * 2 + col, sR + oo);
  }
  __syncthreads();

  {
    const unsigned short* R16 = (const unsigned short*)sR;
#pragma unroll
    for (int it = 0; it < 8; ++it) {
      int cid = it * 256 + t;
      int n = cid & 127, kc16 = (cid >> 7) & 15;
      unsigned short v[8];
#pragma unroll
      for (int j = 0; j < 8; ++j) v[j] = R16[(kc16 * 8 + j) * 128 + n];
      unsigned u4[4];
#pragma unroll
      for (int i = 0; i < 4; ++i)
        u4[i] = (unsigned)v[2 * i] | ((unsigned)v[2 * i + 1] << 16);
      *(uint4*)(sB + n * 256 + ((kc16 * 16) ^ ((n & 7) << 4))) = *(uint4*)&u4[0];
    }
  }
  __syncthreads();

  f32x4 acc[4][2];
#pragma unroll
  for (int ct = 0; ct < 4; ++ct)
#pragma unroll
    for (int jf = 0; jf < 2; ++jf) acc[ct][jf] = (f32x4){0.f, 0.f, 0.f, 0.f};
  int nw = wave * 32;
#pragma unroll
  for (int kc = 0; kc < 4; ++kc) {
    bf16x8 bq[2];
#pragma unroll
    for (int jf = 0; jf < 2; ++jf)
      bq[jf] = lds_fragP(sB, nw + jf * 16 + c, kc * 64 + g * 16, 256);
#pragma unroll
    for (int ct = 0; ct < 4; ++ct) {
      bf16x8 a = lds_fragP(sW, ct * 16 + c, kc * 64 + g * 16, 256);
#pragma unroll
      for (int jf = 0; jf < 2; ++jf)
        acc[ct][jf] = __builtin_amdgcn_mfma_f32_16x16x32_bf16(a, bq[jf], acc[ct][jf], 0, 0, 0);
    }
  }
  __syncthreads();

  char* dmp = sR;
#pragma unroll
  for (int ct = 0; ct < 4; ++ct)
#pragma unroll
    for (int jf = 0; jf < 2; ++jf) {
      int n = nw + jf * 16 + c;
      uint2 wv;
      wv.x = pk_bf16(acc[ct][jf][0], acc[ct][jf][1]);
      wv.y = pk_bf16(acc[ct][jf][2], acc[ct][jf][3]);
      *(uint2*)(dmp + n * 144 + (ct * 16 + 4 * g) * 2) = wv;
    }
  __syncthreads();

  if (qv == 0) {
    int nr = t >> 1, seg = t & 1;
    const char* src = dmp + nr * 144 + seg * 64;
    unsigned short* dst = fqb + ((size_t)bh * NPOS + n0 + nr) * 64 + seg * 32;
#pragma unroll
    for (int i = 0; i < 4; ++i)
      *(uint4*)(dst + i * 8) = *(const uint4*)(src + i * 16);
  } else {
#pragma unroll
    for (int it = 0; it < 2; ++it) {
      int idx = it * 256 + t;
      int dh = idx >> 3, nseg = (idx & 7) * 16;
      unsigned pkv[8];
#pragma unroll
      for (int i = 0; i < 8; ++i) {
        unsigned short lo = *(const unsigned short*)(dmp + (nseg + 2 * i) * 144 + dh * 2);
        unsigned short hi = *(const unsigned short*)(dmp + (nseg + 2 * i + 1) * 144 + dh * 2);
        pkv[i] = (unsigned)lo | ((unsigned)hi << 16);
      }
      unsigned short* dst = fvTb + ((size_t)bh * 64 + dh) * NPOS + n0 + nseg;
      *(uint4*)(dst) = *(uint4*)&pkv[0];
      *(uint4*)(dst + 8) = *(uint4*)&pkv[4];
    }
  }
}

// ================= FUSED ATTENTION (512 threads, 8 waves) ==================
// round-16 schedule + exp2 softmax; row [0,432), col [432,864)
__global__ __launch_bounds__(512, 4) void k_attn(const unsigned short* __restrict__ fqb,
                                                 const unsigned short* __restrict__ fvTb,
                                                 const unsigned short* __restrict__ mapqb,
                                                 const unsigned short* __restrict__ mapvTb,
                                                 unsigned short* __restrict__ F,
                                                 float* __restrict__ Gc,
                                                 float* __restrict__ Gl) {
  __shared__ __align__(16) char sAll[70656];  // [0,32K) dbuf | sP | sL
  char* sPool = sAll;
  unsigned (*sP)[2][16][36] = (unsigned (*)[2][16][36])(sAll + 32768);
  float (*sL)[2][16] = (float (*)[2][16])(sAll + 32768 + 36864);
  int bid = blockIdx.x;
  int t = threadIdx.x, wave = t >> 6, lane = t & 63, g = lane >> 4, c = lane & 15;

  if (bid < 432) {  // ========== ROW PASS ==========
    int jblk = bid % 54, bh = bid / 54;
    int j0 = jblk * 256 + wave * 32;

    const char* Kg = (const char*)(mapqb + (size_t)bh * MPOS * 64);
    const char* Vg = (const char*)(mapvTb + (size_t)bh * 64 * MPOS);

    const unsigned short* fqp = fqb + ((size_t)bh * NPOS + j0 + c) * 64 + 8 * g;
    bf16x8 bq00 = *(const bf16x8*)(fqp);
    bf16x8 bq01 = *(const bf16x8*)(fqp + 32);
    bf16x8 bq10 = *(const bf16x8*)(fqp + 16 * 64);
    bf16x8 bq11 = *(const bf16x8*)(fqp + 16 * 64 + 32);

    f32x4 o[2][4];
#pragma unroll
    for (int jf = 0; jf < 2; ++jf)
#pragma unroll
      for (int dt = 0; dt < 4; ++dt) o[jf][dt] = (f32x4){0.f, 0.f, 0.f, 0.f};
    float ls0 = 0.f, ls1 = 0.f;

    {
      int oo = t * 16;
      int row = oo >> 7, col = (oo & 127) ^ (((oo >> 7) & 7) << 4);
      GL2LDS(Kg + (size_t)row * 128 + col, sPool + oo);
      GL2LDS(Vg + (size_t)row * 1024 + col, sPool + 16384 + oo);
    }
    __syncthreads();

    for (int ic = 0; ic < 8; ++ic) {
      const char* Kt = sPool + (ic & 1) * 8192;
      const char* Vt = sPool + 16384 + (ic & 1) * 8192;
      if (ic < 7) {
        int ibase = (ic + 1) * 64;
        int bsel = ((ic + 1) & 1) * 8192;
        int oo = t * 16;
        int row = oo >> 7, col = (oo & 127) ^ (((oo >> 7) & 7) << 4);
        GL2LDS(Kg + (size_t)(ibase + row) * 128 + col, sPool + bsel + oo);
        GL2LDS(Vg + (size_t)row * 1024 + ibase * 2 + col, sPool + 16384 + bsel + oo);
      }
#pragma unroll
      for (int ti = 0; ti < 4; ++ti) {
        bf16x8 a0 = lds_frag(Kt, ti * 16 + c, 16 * g);
        bf16x8 a1 = lds_frag(Kt, ti * 16 + c, 64 + 16 * g);
        f32x4 s0 = {0.f, 0.f, 0.f, 0.f}, s1 = {0.f, 0.f, 0.f, 0.f};
        s0 = __builtin_amdgcn_mfma_f32_16x16x32_bf16(a0, bq00, s0, 0, 0, 0);
        s0 = __builtin_amdgcn_mfma_f32_16x16x32_bf16(a1, bq01, s0, 0, 0, 0);
        s1 = __builtin_amdgcn_mfma_f32_16x16x32_bf16(a0, bq10, s1, 0, 0, 0);
        s1 = __builtin_amdgcn_mfma_f32_16x16x32_bf16(a1, bq11, s1, 0, 0, 0);
        float p0 = __builtin_amdgcn_exp2f(s0[0]), p1 = __builtin_amdgcn_exp2f(s0[1]);
        float p2 = __builtin_amdgcn_exp2f(s0[2]), p3 = __builtin_amdgcn_exp2f(s0[3]);
        ls0 += (p0 + p1) + (p2 + p3);
        sP[wave][0][c][ti * 8 + 2 * g] = pk_bf16(p0, p1);
        sP[wave][0][c][ti * 8 + 2 * g + 1] = pk_bf16(p2, p3);
        float q0 = __builtin_amdgcn_exp2f(s1[0]), q1 = __builtin_amdgcn_exp2f(s1[1]);
        float q2 = __builtin_amdgcn_exp2f(s1[2]), q3 = __builtin_amdgcn_exp2f(s1[3]);
        ls1 += (q0 + q1) + (q2 + q3);
        sP[wave][1][c][ti * 8 + 2 * g] = pk_bf16(q0, q1);
        sP[wave][1][c][ti * 8 + 2 * g + 1] = pk_bf16(q2, q3);
      }
#pragma unroll
      for (int ks = 0; ks < 2; ++ks) {
        bf16x8 ap0 = *(const bf16x8*)&sP[wave][0][c][ks * 16 + 4 * g];
        bf16x8 ap1 = *(const bf16x8*)&sP[wave][1][c][ks * 16 + 4 * g];
#pragma unroll
        for (int dt = 0; dt < 4; ++dt) {
          bf16x8 bv = lds_frag(Vt, dt * 16 + c, ks * 64 + 16 * g);
          o[0][dt] = __builtin_amdgcn_mfma_f32_16x16x32_bf16(ap0, bv, o[0][dt], 0, 0, 0);
          o[1][dt] = __builtin_amdgcn_mfma_f32_16x16x32_bf16(ap1, bv, o[1][dt], 0, 0, 0);
        }
      }
      __syncthreads();
    }

    ls0 += __shfl_xor(ls0, 16); ls0 += __shfl_xor(ls0, 32);
    ls1 += __shfl_xor(ls1, 16); ls1 += __shfl_xor(ls1, 32);
    if (g == 0) { sL[wave][0][c] = 1.f / ls0; sL[wave][1][c] = 1.f / ls1; }
#pragma unroll
    for (int jf = 0; jf < 2; ++jf) {
      float rl0 = sL[wave][jf][4 * g + 0], rl1 = sL[wave][jf][4 * g + 1];
      float rl2 = sL[wave][jf][4 * g + 2], rl3 = sL[wave][jf][4 * g + 3];
#pragma unroll
      for (int dt = 0; dt < 4; ++dt) {
        uint2 wv;
        wv.x = pk_bf16(o[jf][dt][0] * rl0, o[jf][dt][1] * rl1);
        wv.y = pk_bf16(o[jf][dt][2] * rl2, o[jf][dt][3] * rl3);
        *(uint2*)(sAll + (dt * 16 + c) * 544 + (wave * 32 + jf * 16 + 4 * g) * 2) = wv;
      }
    }
    __syncthreads();
    {
      int ch = t >> 3, seg = t & 7;
      int b = bh >> 2, head = bh & 3;
      unsigned short* dst = F + ((size_t)b * INNER + head * 64 + ch) * NPOS +
                            jblk * 256 + seg * 32;
      const char* src = sAll + ch * 544 + seg * 64;
#pragma unroll
      for (int i = 0; i < 4; ++i)
        *(uint4*)(dst + i * 8) = *(const uint4*)(src + i * 16);
    }
  } else {  // ========== COL PASS (bh-fastest for XCD pinning) ==========
    int cid = bid - 432;
    int bh = cid & 7, iblk = (cid >> 3) & 1, chunk = cid >> 4;
    char* sQ = sPool;
    char* sV = sPool + 16384;
    int i0 = iblk * 256 + wave * 32;
    int jb = chunk * JCHUNK;

    const char* Qg = (const char*)(fqb + (size_t)bh * NPOS * 64);
    const char* Vg = (const char*)(fvTb + (size_t)bh * 64 * NPOS);

    const unsigned short* kp = mapqb + ((size_t)bh * MPOS + i0 + c) * 64 + 8 * g;
    bf16x8 bm00 = *(const bf16x8*)(kp);
    bf16x8 bm01 = *(const bf16x8*)(kp + 32);
    bf16x8 bm10 = *(const bf16x8*)(kp + 16 * 64);
    bf16x8 bm11 = *(const bf16x8*)(kp + 16 * 64 + 32);

    f32x4 o[2][4];
#pragma unroll
    for (int f = 0; f < 2; ++f)
#pragma unroll
      for (int dt = 0; dt < 4; ++dt) o[f][dt] = (f32x4){0.f, 0.f, 0.f, 0.f};
    float lc0 = 0.f, lc1 = 0.f;

    {
      int oo = t * 16;
      int row = oo >> 7, col = (oo & 127) ^ (((oo >> 7) & 7) << 4);
      GL2LDS(Qg + (size_t)(jb + row) * 128 + col, sQ + oo);
      GL2LDS(Vg + (size_t)row * (NPOS * 2) + jb * 2 + col, sV + oo);
    }
    __syncthreads();

    for (int jc = 0; jc < JCHUNK / 64; ++jc) {
      const char* Qt = sQ + (jc & 1) * 8192;
      const char* Vt = sV + (jc & 1) * 8192;
      if (jc < JCHUNK / 64 - 1) {
        int jbase = jb + (jc + 1) * 64;
        int bsel = ((jc + 1) & 1) * 8192;
        int oo = t * 16;
        int row = oo >> 7, col = (oo & 127) ^ (((oo >> 7) & 7) << 4);
        GL2LDS(Qg + (size_t)(jbase + row) * 128 + col, sQ + bsel + oo);
        GL2LDS(Vg + (size_t)row * (NPOS * 2) + jbase * 2 + col, sV + bsel + oo);
      }
#pragma unroll
      for (int tj = 0; tj < 4; ++tj) {
        bf16x8 a0 = lds_frag(Qt, tj * 16 + c, 16 * g);
        bf16x8 a1 = lds_frag(Qt, tj * 16 + c, 64 + 16 * g);
        f32x4 s0 = {0.f, 0.f, 0.f, 0.f}, s1 = {0.f, 0.f, 0.f, 0.f};
        s0 = __builtin_amdgcn_mfma_f32_16x16x32_bf16(a0, bm00, s0, 0, 0, 0);
        s0 = __builtin_amdgcn_mfma_f32_16x16x32_bf16(a1, bm01, s0, 0, 0, 0);
        s1 = __builtin_amdgcn_mfma_f32_16x16x32_bf16(a0, bm10, s1, 0, 0, 0);
        s1 = __builtin_amdgcn_mfma_f32_16x16x32_bf16(a1, bm11, s1, 0, 0, 0);
        float p0 = __builtin_amdgcn_exp2f(s0[0]), p1 = __builtin_amdgcn_exp2f(s0[1]);
        float p2 = __builtin_amdgcn_exp2f(s0[2]), p3 = __builtin_amdgcn_exp2f(s0[3]);
        lc0 += (p0 + p1) + (p2 + p3);
        sP[wave][0][c][tj * 8 + 2 * g] = pk_bf16(p0, p1);
        sP[wave][0][c][tj * 8 + 2 * g + 1] = pk_bf16(p2, p3);
        float q0 = __builtin_amdgcn_exp2f(s1[0]), q1 = __builtin_amdgcn_exp2f(s1[1]);
        float q2 = __builtin_amdgcn_exp2f(s1[2]), q3 = __builtin_amdgcn_exp2f(s1[3]);
        lc1 += (q0 + q1) + (q2 + q3);
        sP[wave][1][c][tj * 8 + 2 * g] = pk_bf16(q0, q1);
        sP[wave][1][c][tj * 8 + 2 * g + 1] = pk_bf16(q2, q3);
      }
#pragma unroll
      for (int ks = 0; ks < 2; ++ks) {
        bf16x8 ap0 = *(const bf16x8*)&sP[wave][0][c][ks * 16 + 4 * g];
        bf16x8 ap1 = *(const bf16x8*)&sP[wave][1][c][ks * 16 + 4 * g];
#pragma unroll
        for (int dt = 0; dt < 4; ++dt) {
          bf16x8 bv = lds_frag(Vt, dt * 16 + c, ks * 64 + 16 * g);
          o[0][dt] = __builtin_amdgcn_mfma_f32_16x16x32_bf16(ap0, bv, o[0][dt], 0, 0, 0);
          o[1][dt] = __builtin_amdgcn_mfma_f32_16x16x32_bf16(ap1, bv, o[1][dt], 0, 0, 0);
        }
      }
      __syncthreads();
    }

    lc0 += __shfl_xor(lc0, 16); lc0 += __shfl_xor(lc0, 32);
    lc1 += __shfl_xor(lc1, 16); lc1 += __shfl_xor(lc1, 32);
    int gi = chunk * 8 + bh;
    if (g == 0) {
      Gl[(size_t)gi * MPOS + i0 + c] = lc0;
      Gl[(size_t)gi * MPOS + i0 + 16 + c] = lc1;
    }
    float* gp = Gc + ((size_t)gi * MPOS + i0) * 64;
#pragma unroll
    for (int f = 0; f < 2; ++f)
#pragma unroll
      for (int dt = 0; dt < 4; ++dt)
#pragma unroll
        for (int r = 0; r < 4; ++r)
          gp[(size_t)(f * 16 + 4 * g + r) * 64 + dt * 16 + c] = o[f][dt][r];
  }
}

// ====== FUSED POST: dwb full-row (blocks [0,1152)) + map_out (rest) ========
__global__ __launch_bounds__(256) void k_post(const unsigned short* __restrict__ F,
                                              const float* __restrict__ fout_dw,
                                              unsigned short* __restrict__ dwt2,
                                              const float* __restrict__ Gc,
                                              const float* __restrict__ Gl,
                                              const float* __restrict__ mow,
                                              float* __restrict__ out2) {
  int bid = blockIdx.x;
  int t = threadIdx.x;
  if (bid < 1152) {  // ---- dwb: one thread = one full x-row (24 outputs) ----
    int row_id = bid * 256 + t;                 // 0 .. 294911
    int bc = row_id / 576;                      // (b,c) plane
    int rr = row_id - bc * 576;                 // z*24+y
    int cc = bc & (INNER - 1), b = bc / INNER;
    int cm = (cc & 63) * 4 + (cc >> 6);
    int y = rr % 24, z = rr / 24;
    const float* wr = fout_dw + cm * 27;
    const unsigned short* ip = F + (size_t)bc * NPOS;

    float w0a[9], w1a[9], w2a[9];
    int ro[9];
#pragma unroll
    for (int dz = 0; dz < 3; ++dz)
#pragma unroll
      for (int dy = 0; dy < 3; ++dy) {
        int r = dz * 3 + dy;
        int zz = z + dz - 1, yy = y + dy - 1;
        bool ok = ((unsigned)zz < 24u) && ((unsigned)yy < 24u);
        w0a[r] = ok ? wr[dz * 9 + dy * 3 + 0] : 0.f;
        w1a[r] = ok ? wr[dz * 9 + dy * 3 + 1] : 0.f;
        w2a[r] = ok ? wr[dz * 9 + dy * 3 + 2] : 0.f;
        int zc = min(max(zz, 0), 23), yc = min(max(yy, 0), 23);
        ro[r] = (zc * 24 + yc) * 24;
      }
    // 27 aligned uint4 loads (no scalar halo loads), one latency window
    uint4 Ru[9][3];
#pragma unroll
    for (int r = 0; r < 9; ++r) {
      const unsigned short* rp = ip + ro[r];
      Ru[r][0] = *(const uint4*)(rp);
      Ru[r][1] = *(const uint4*)(rp + 8);
      Ru[r][2] = *(const uint4*)(rp + 16);
    }
    float acc[24];
#pragma unroll
    for (int i = 0; i < 24; ++i) acc[i] = 0.f;
#pragma unroll
    for (int r = 0; r < 9; ++r) {
      float x[24];
#pragma unroll
      for (int k = 0; k < 3; ++k) {
        unsigned u0 = Ru[r][k].x, u1 = Ru[r][k].y, u2 = Ru[r][k].z, u3 = Ru[r][k].w;
        x[k * 8 + 0] = __builtin_bit_cast(float, (u0 & 0xFFFFu) << 16);
        x[k * 8 + 1] = __builtin_bit_cast(float, u0 & 0xFFFF0000u);
        x[k * 8 + 2] = __builtin_bit_cast(float, (u1 & 0xFFFFu) << 16);
        x[k * 8 + 3] = __builtin_bit_cast(float, u1 & 0xFFFF0000u);
        x[k * 8 + 4] = __builtin_bit_cast(float, (u2 & 0xFFFFu) << 16);
        x[k * 8 + 5] = __builtin_bit_cast(float, u2 & 0xFFFF0000u);
        x[k * 8 + 6] = __builtin_bit_cast(float, (u3 & 0xFFFFu) << 16);
        x[k * 8 + 7] = __builtin_bit_cast(float, u3 & 0xFFFF0000u);
      }
      float w0 = w0a[r], w1 = w1a[r], w2 = w2a[r];
      acc[0] += w1 * x[0] + w2 * x[1];
#pragma unroll
      for (int i = 1; i < 23; ++i)
        acc[i] += w0 * x[i - 1] + w1 * x[i] + w2 * x[i + 1];
      acc[23] += w0 * x[22] + w1 * x[23];
    }
    unsigned short* op = dwt2 + ((size_t)b * INNER + cm) * NPOS + rr * 24;
    unsigned pk[12];
#pragma unroll
    for (int i = 0; i < 12; ++i) pk[i] = pk_bf16(acc[2 * i], acc[2 * i + 1]);
    *(uint4*)(op) = *(uint4*)&pk[0];
    *(uint4*)(op + 8) = *(uint4*)&pk[4];
    *(uint4*)(op + 16) = *(uint4*)&pk[8];
  } else {  // ---- combine col partials + map_out projection ----
    int mi = bid - 1152;
    int m = mi & 511, b = mi >> 9;
    __shared__ float sMA[256];
    __shared__ float sL2[4];
    if (t < 4) {
      float l = 0.f;
#pragma unroll 4
      for (int ch = 0; ch < JSPLIT; ++ch)
        l += Gl[(size_t)(ch * 8 + b * 4 + t) * MPOS + m];
      sL2[t] = 1.f / l;
    }
    __syncthreads();
    {
      int head = t & 3, dh = t >> 2;
      int bh = b * 4 + head;
      float a = 0.f;
#pragma unroll 4
      for (int ch = 0; ch < JSPLIT; ++ch)
        a += Gc[((size_t)(ch * 8 + bh) * MPOS + m) * 64 + dh];
      sMA[t] = a * sL2[head];
    }
    __syncthreads();
    if (t < 64) {
      const float* wr = mow + t * 256;
      float acc = 0.f;
#pragma unroll 4
      for (int c = 0; c < 256; ++c) acc += wr[c] * sMA[c];
      out2[((size_t)b * 64 + t) * MPOS + m] = acc;
    }
  }
}

// ---------------- MFMA pointwise out GEMM (fused in-LDS transpose) --------
__global__ __launch_bounds__(256) void k_pwout_m(const unsigned short* __restrict__ dwo,
                                                 const float* __restrict__ pw,
                                                 float* __restrict__ out1) {
  __shared__ __align__(16) char sW[32768];
  __shared__ __align__(16) char sB[32768];
  __shared__ __align__(16) char sR[16384];
  int t = threadIdx.x, wave = t >> 6, lane = t & 63, g = lane >> 4, c = lane & 15;
  int n0 = blockIdx.x * 128, ti = blockIdx.y, b = blockIdx.z;

  {
    int r = t >> 2, ks = (t & 3) * 64;
    const float* wp = pw + (size_t)(ti * 64 + r) * 256 + ks;
    unsigned pkv[32];
#pragma unroll
    for (int i = 0; i < 16; ++i) {
      float4 v = *(const float4*)(wp + i * 4);
      pkv[2 * i] = pk_bf16(v.x, v.y);
      pkv[2 * i + 1] = pk_bf16(v.z, v.w);
    }
#pragma unroll
    for (int u = 0; u < 8; ++u) {
      int colb = (ks * 2 + u * 16) ^ ((r & 7) << 4);
      *(uint4*)(sW + r * 512 + colb) = *(uint4*)&pkv[u * 4];
    }
  }

  f32x4 acc[4][2];
#pragma unroll
  for (int ct = 0; ct < 4; ++ct)
#pragma unroll
    for (int jf = 0; jf < 2; ++jf) acc[ct][jf] = (f32x4){0.f, 0.f, 0.f, 0.f};
  int nw = wave * 32;
  const char* Bgc = (const char*)(dwo + (size_t)b * INNER * NPOS);
  const unsigned short* R16 = (const unsigned short*)sR;

  for (int kh = 0; kh < 2; ++kh) {
#pragma unroll
    for (int q = 0; q < 2; ++q) {
#pragma unroll
      for (int p = 0; p < 4; ++p) {
        int oo = p * 4096 + t * 16;
        int kl = oo >> 8, col = oo & 255;
        GL2LDS(Bgc + (size_t)(kh * 128 + q * 64 + kl) * (NPOS * 2) + n0 * 2 + col,
               sR + oo);
      }
      __syncthreads();
#pragma unroll
      for (int it = 0; it < 4; ++it) {
        int cid = it * 256 + t;
        int n = cid & 127, kcl = (cid >> 7) & 7;
        unsigned short v[8];
#pragma unroll
        for (int j = 0; j < 8; ++j) v[j] = R16[(kcl * 8 + j) * 128 + n];
        unsigned u4[4];
#pragma unroll
        for (int i = 0; i < 4; ++i)
          u4[i] = (unsigned)v[2 * i] | ((unsigned)v[2 * i + 1] << 16);
        int kc16 = q * 8 + kcl;
        *(uint4*)(sB + n * 256 + ((kc16 * 16) ^ ((n & 7) << 4))) = *(uint4*)&u4[0];
      }
      __syncthreads();
    }
#pragma unroll
    for (int kc = 0; kc < 4; ++kc) {
      bf16x8 bq[2];
#pragma unroll
      for (int jf = 0; jf < 2; ++jf)
        bq[jf] = lds_fragP(sB, nw + jf * 16 + c, kc * 64 + g * 16, 256);
#pragma unroll
      for (int ct = 0; ct < 4; ++ct) {
        bf16x8 a = lds_fragP(sW, ct * 16 + c, (kh * 4 + kc) * 64 + g * 16, 512);
#pragma unroll
        for (int jf = 0; jf < 2; ++jf)
          acc[ct][jf] = __builtin_amdgcn_mfma_f32_16x16x32_bf16(a, bq[jf], acc[ct][jf], 0, 0, 0);
      }
    }
    __syncthreads();
  }
#pragma unroll
  for (int ct = 0; ct < 4; ++ct)
#pragma unroll
    for (int jf = 0; jf < 2; ++jf) {
      int n = n0 + nw + jf * 16 + c;
#pragma unroll
      for (int r = 0; r < 4; ++r) {
        int co = ti * 64 + ct * 16 + 4 * g + r;
        out1[((size_t)b * 128 + co) * NPOS + n] = acc[ct][jf][r];
      }
    }
}

extern "C" void kernel_launch(void* const* d_in, const int* in_sizes, int n_in,
                              void* d_out, int out_size, void* d_ws, size_t ws_size,
                              hipStream_t stream) {
  const float* feat = (const float*)d_in[0];
  const float* smap = (const float*)d_in[1];
  const float* fqv_dw = (const float*)d_in[2];
  const float* fqv_pw = (const float*)d_in[3];
  const float* fout_dw = (const float*)d_in[4];
  const float* fout_pw = (const float*)d_in[5];
  const float* mqv_w = (const float*)d_in[6];
  const float* mout_w = (const float*)d_in[7];

  float* out = (float*)d_out;
  float* out1 = out;                              // [2,128,24,24,24]
  float* out2 = out + (size_t)BB * 128 * NPOS;    // [2,64,8,8,8]

  const size_t QV = (size_t)BB * HEADS * NPOS * DH;   // 7,077,888
  const size_t MQV = (size_t)BB * HEADS * MPOS * DH;  // 262,144
  float* ws = (float*)d_ws;
  unsigned short* F = (unsigned short*)ws;             // bf16 attn row output
  unsigned short* fqb = (unsigned short*)(ws + QV);    // bf16 [bh][j][d]
  unsigned short* fvTb = fqb + QV;                     // bf16 [bh][d][j]
  unsigned short* mapqb = fvTb + QV;                   // bf16 [bh][i][d] (scaled)
  unsigned short* mapvTb = mapqb + MQV;                // bf16 [bh][d][i]
  float* Gc = (float*)(mapvTb + MQV);                  // [JSPLIT*8][512][64]
  float* Gl = Gc + (size_t)JSPLIT * 8 * MPOS * 64;     // [JSPLIT*8][512]

  // lifetime-disjoint aliases
  unsigned short* dwt = (unsigned short*)out1;  // dw1 out bf16; dead after pwqv
  unsigned short* dwt2 = fqb;                   // dw2 out bf16; fq dead after attn

  k_pre<<<dim3(1024 + BB * CH_FEAT * 1728 / 256), dim3(256), 0, stream>>>(
      smap, mqv_w, mapqb, mapvTb, feat, fqv_dw, dwt);
  k_pwqv_m<<<dim3(NPOS / 128, 8, BB), dim3(256), 0, stream>>>(dwt, fqv_pw, fqb, fvTb);
  k_attn<<<dim3(432 + 8 * 2 * JSPLIT), dim3(512), 0, stream>>>(
      fqb, fvTb, mapqb, mapvTb, F, Gc, Gl);
  k_post<<<dim3(1152 + BB * MPOS), dim3(256), 0, stream>>>(
      F, fout_dw, dwt2, Gc, Gl, mout_w, out2);
  k_pwout_m<<<dim3(NPOS / 128, 2, BB), dim3(256), 0, stream>>>(dwt2, fout_pw, out1);
}